// Round 5
// baseline (171.701 us; speedup 1.0000x reference)
//
#include <hip/hip_runtime.h>

#define BATCH 8
#define CIN 128
#define OCH 128
#define T_LEN 16384
#define NS 256
#define CHUNK 64
#define NCHUNK (T_LEN / CHUNK)   // 256
#define THALF (T_LEN / 2)        // 8192
#define SCHUNK 8192              // u32 per chunk image: 32 t-pair rows x 256 n
#define HROW 132                 // Hr row stride (u32)

typedef __attribute__((ext_vector_type(8))) short bf16x8;
typedef __attribute__((ext_vector_type(4))) float f32x4;
typedef __attribute__((ext_vector_type(4))) unsigned int u32x4;

__device__ __forceinline__ unsigned int pk2(float lo, float hi) {
  unsigned int d;
  asm("v_cvt_pk_bf16_f32 %0, %1, %2" : "=v"(d) : "v"(lo), "v"(hi));
  return d;
}
__device__ __forceinline__ float bf2f(unsigned int h) {
  return __uint_as_float(h << 16);
}
__device__ __forceinline__ unsigned short f2bf(float f) {
  unsigned int u = __float_as_uint(f);
  u += 0x7fffu + ((u >> 16) & 1u);
  return (unsigned short)(u >> 16);
}
__device__ __forceinline__ float softplusf_(float v) {
  return (v > 20.0f) ? v : log1pf(expf(v));
}

// ---------------- prep: weights -> bf16, A_d, A_d^L, PW[t][n] = A_n^(t+1) ----------------
__global__ __launch_bounds__(256) void k_prep(
    const float* __restrict__ rl, const float* __restrict__ Bc,
    const float* __restrict__ Cm, const float* __restrict__ W,
    unsigned short* __restrict__ BdT, unsigned short* __restrict__ CT,
    unsigned short* __restrict__ Wb, float* __restrict__ Ad, float* __restrict__ rL,
    unsigned int* __restrict__ PW2)
{
  const int tid = blockIdx.x * 256 + threadIdx.x;
  if (tid < NS * CIN) {                       // BdT[n][c] = B_c[c][n] * (A_d-1)/lam
    const int n = tid >> 7, c = tid & 127;
    float lam = -softplusf_(rl[n]);
    float ad = expf(lam);
    float sc = (ad - 1.0f) / lam;
    BdT[tid] = f2bf(Bc[c * NS + n] * sc);
  } else if (tid < 2 * NS * CIN) {            // CT[o][n] = C[n][o]
    const int i = tid - NS * CIN;
    const int o = i >> 8, n = i & 255;
    CT[i] = f2bf(Cm[n * OCH + o]);
  } else if (tid < 3 * NS * CIN) {            // Wb[o][c2] = W[o][c2]
    const int i = tid - 2 * NS * CIN;
    Wb[i] = f2bf(W[i]);
  } else if (tid < 3 * NS * CIN + NS) {
    const int n = tid - 3 * NS * CIN;
    float lam = -softplusf_(rl[n]);
    Ad[n] = expf(lam);
    rL[n] = expf(lam * (float)CHUNK);
  } else if (tid < 3 * NS * CIN + NS + 64 * 128) {  // PW2[t][np] = pk(A_{2np}^{t+1}, A_{2np+1}^{t+1})
    const int i = tid - (3 * NS * CIN + NS);
    const int t = i >> 7, np = i & 127;
    float lam0 = -softplusf_(rl[2 * np]);
    float lam1 = -softplusf_(rl[2 * np + 1]);
    PW2[i] = pk2(expf(lam0 * (float)(t + 1)), expf(lam1 * (float)(t + 1)));
  }
}

// ---------------- chunk-carry combine: Hillis-Steele with multiplier A^L ----------------
__global__ __launch_bounds__(256) void k_combine(float* __restrict__ carry,
                                                 const float* __restrict__ rL)
{
  const int b = blockIdx.x >> 3;
  const int ng = blockIdx.x & 7;      // n-group of 32
  const int t = threadIdx.x;          // chunk index
  __shared__ float Y[32][NCHUNK];
  float* base = carry + ((size_t)b * NCHUNK + t) * NS + ng * 32;
  #pragma unroll
  for (int i4 = 0; i4 < 8; ++i4) {
    float4 q = *(const float4*)(base + i4 * 4);
    Y[i4 * 4 + 0][t] = q.x; Y[i4 * 4 + 1][t] = q.y;
    Y[i4 * 4 + 2][t] = q.z; Y[i4 * 4 + 3][t] = q.w;
  }
  float rp[32];
  #pragma unroll
  for (int i = 0; i < 32; ++i) rp[i] = rL[ng * 32 + i];
  __syncthreads();
  for (int d = 1; d < NCHUNK; d <<= 1) {
    float tmp[32];
    #pragma unroll
    for (int i = 0; i < 32; ++i) tmp[i] = (t >= d) ? Y[i][t - d] : 0.0f;
    __syncthreads();
    #pragma unroll
    for (int i = 0; i < 32; ++i) { Y[i][t] += rp[i] * tmp[i]; rp[i] *= rp[i]; }
    __syncthreads();
  }
  const int tm = (t == 0) ? 0 : (t - 1);
  #pragma unroll
  for (int i4 = 0; i4 < 8; ++i4) {
    float a = Y[i4 * 4 + 0][tm], bb = Y[i4 * 4 + 1][tm];
    float c = Y[i4 * 4 + 2][tm], dd = Y[i4 * 4 + 3][tm];
    float4 q;
    q.x = (t == 0) ? 0.0f : a;  q.y = (t == 0) ? 0.0f : bb;
    q.z = (t == 0) ? 0.0f : c;  q.w = (t == 0) ? 0.0f : dd;
    *(float4*)(base + i4 * 4) = q;
  }
}

// ---------------- k_scan: x -> v-GEMM -> scan(seed 0) -> s0 scratch + totals ----------------
__global__ __launch_bounds__(512, 4) void k_scan(
    const float* __restrict__ x,
    const unsigned short* __restrict__ BdT,
    const float* __restrict__ Ad,
    unsigned int* __restrict__ s0,
    float* __restrict__ carry)
{
  const int bid = blockIdx.x;
  const int b = bid >> 8;
  const int kc = bid & 255;
  const int tid = threadIdx.x;
  const int w = tid >> 6, l = tid & 63, l15 = l & 15, g = l >> 4;

  __shared__ __align__(16) unsigned int Xt[64 * 64];  // [t][c2 ^ ((t&7)<<2)] packed bf16 pairs

  // ---- stage x: thread -> (c2 = w*8 + (l&7), t = (l>>3) + 8k) ----
  {
    const int c2 = w * 8 + (l & 7);
    const int tb = l >> 3;
    const float* r0 = x + ((size_t)(b * CIN + 2 * c2)) * T_LEN + kc * CHUNK + tb;
    float xa[8], xb[8];
    #pragma unroll
    for (int k = 0; k < 8; ++k) {
      xa[k] = r0[8 * k];
      xb[k] = r0[(size_t)T_LEN + 8 * k];
    }
    #pragma unroll
    for (int k = 0; k < 8; ++k) {
      const int t = tb + 8 * k;
      Xt[t * 64 + (c2 ^ ((t & 7) << 2))] = pk2(xa[k], xb[k]);
    }
  }

  // ---- per-wave B fragments (n in [32w, 32w+32)) + scan constants ----
  bf16x8 Bf[2][4];
  #pragma unroll
  for (int nt = 0; nt < 2; ++nt)
    #pragma unroll
    for (int kt = 0; kt < 4; ++kt)
      Bf[nt][kt] = *(const bf16x8*)&BdT[(w * 32 + nt * 16 + l15) * CIN + kt * 32 + g * 8];

  float A1[2], A2[2], A3[2], A4[2], A8[2], A16[2], A4G[2], M1[2], M2[2];
  #pragma unroll
  for (int nt = 0; nt < 2; ++nt) {
    const float a1 = Ad[w * 32 + nt * 16 + l15];
    A1[nt] = a1; A2[nt] = a1 * a1; A3[nt] = A2[nt] * a1; A4[nt] = A2[nt] * A2[nt];
    A8[nt] = A4[nt] * A4[nt]; A16[nt] = A8[nt] * A8[nt];
    float a4g = 1.0f;
    if (g & 1) a4g *= A4[nt];
    if (g & 2) a4g *= A8[nt];
    A4G[nt] = a4g;
    M1[nt] = (g >= 1) ? A4[nt] : 0.0f;
    M2[nt] = (g >= 2) ? A8[nt] : 0.0f;
  }
  __syncthreads();

  // ---- v-GEMM ----
  f32x4 vac[4][2] = {};
  #pragma unroll
  for (int kt = 0; kt < 4; ++kt) {
    bf16x8 afr[4];
    #pragma unroll
    for (int mt = 0; mt < 4; ++mt)
      afr[mt] = *(const bf16x8*)&Xt[(mt * 16 + l15) * 64 + ((kt * 16 + g * 4) ^ ((l15 & 7) << 2))];
    #pragma unroll
    for (int nt = 0; nt < 2; ++nt)
      #pragma unroll
      for (int mt = 0; mt < 4; ++mt)
        vac[mt][nt] = __builtin_amdgcn_mfma_f32_16x16x32_bf16(afr[mt], Bf[nt][kt], vac[mt][nt], 0, 0, 0);
  }

  // ---- in-register scan over t, seed 0 ----
  float crv[2];
  #pragma unroll
  for (int nt = 0; nt < 2; ++nt) {
    float cr = 0.0f;
    #pragma unroll
    for (int mt = 0; mt < 4; ++mt) {
      const float p0 = vac[mt][nt][0];
      const float p1 = fmaf(A1[nt], p0, vac[mt][nt][1]);
      const float p2 = fmaf(A1[nt], p1, vac[mt][nt][2]);
      const float p3 = fmaf(A1[nt], p2, vac[mt][nt][3]);
      float c0 = p3;
      float u = __shfl_up(c0, 16);
      c0 = fmaf(M1[nt], u, c0);
      u = __shfl_up(c0, 32);
      c0 = fmaf(M2[nt], u, c0);
      float e = __shfl_up(c0, 16);
      e = (g == 0) ? 0.0f : e;
      const float seed = fmaf(A4G[nt], cr, e);
      vac[mt][nt][0] = fmaf(A1[nt], seed, p0);
      vac[mt][nt][1] = fmaf(A2[nt], seed, p1);
      vac[mt][nt][2] = fmaf(A3[nt], seed, p2);
      vac[mt][nt][3] = fmaf(A4[nt], seed, p3);
      const float ctop = __shfl(c0, 48 + l15);
      cr = fmaf(A16[nt], cr, ctop);
    }
    crv[nt] = cr;
  }

  // ---- store packed s0 [tp][n] + totals ----
  unsigned int* sc = s0 + (size_t)(b * NCHUNK + kc) * SCHUNK;
  #pragma unroll
  for (int mt = 0; mt < 4; ++mt)
    #pragma unroll
    for (int nt = 0; nt < 2; ++nt) {
      const int n = w * 32 + nt * 16 + l15;
      #pragma unroll
      for (int rp = 0; rp < 2; ++rp) {
        const int tp = mt * 8 + g * 2 + rp;
        sc[tp * 256 + n] = pk2(vac[mt][nt][rp * 2], vac[mt][nt][rp * 2 + 1]);
      }
    }
  if (g == 0) {
    #pragma unroll
    for (int nt = 0; nt < 2; ++nt)
      carry[((size_t)b * NCHUNK + kc) * NS + (w * 32 + nt * 16 + l15)] = crv[nt];
  }
}

// ---------------- k_apply: single chunk/block; y = s0*C + PW*diag(seed)*C -> LN/SiLU -> out ----------------
__global__ __launch_bounds__(512, 4) void k_apply(
    const unsigned int* __restrict__ S,
    const unsigned short* __restrict__ CT,
    const unsigned short* __restrict__ Wb,
    const unsigned int* __restrict__ PW2,
    const float* __restrict__ carry,
    const float* __restrict__ lng, const float* __restrict__ lnb,
    const float* __restrict__ bias,
    float* __restrict__ out)
{
  const int bid = blockIdx.x;
  const int b = bid >> 8, kc = bid & 255;
  const int tid = threadIdx.x;
  const int w = tid >> 6, l = tid & 63, l15 = l & 15, g = l >> 4;
  const int tt = w >> 2, oq = w & 3;   // y tiling: wave = (t-32-block, o-32-block)

  __shared__ __align__(16) unsigned int Hr[32 * HROW];  // 16.9 KB
  __shared__ __align__(16) float Lexf[64 * 8];          // 2 KB

  const unsigned int* scb = S + (size_t)(b * NCHUNK + kc) * SCHUNK;
  const float* seedp = carry + ((size_t)b * NCHUNK + kc) * NS;
  const unsigned int sel = (l15 & 1) ? 0x07060302u : 0x05040100u;

  // ---- y-GEMM + folded seed correction (all operands from global/L2/L3) ----
  f32x4 yac[2][2] = {};
  #pragma unroll
  for (int kt = 0; kt < 8; ++kt) {
    const int n0 = kt * 32 + g * 8;
    const f32x4 sd0 = *(const f32x4*)&seedp[n0];
    const f32x4 sd1 = *(const f32x4*)&seedp[n0 + 4];
    bf16x8 As[2], Ps[2];
    #pragma unroll
    for (int mt = 0; mt < 2; ++mt) {
      const int t = tt * 32 + mt * 16 + l15;
      const u32x4 q0 = *(const u32x4*)&scb[(t >> 1) * 256 + n0];
      const u32x4 q1 = *(const u32x4*)&scb[(t >> 1) * 256 + n0 + 4];
      union { bf16x8 v; unsigned int u[4]; } Aa;
      Aa.u[0] = __builtin_amdgcn_perm(q0[1], q0[0], sel);
      Aa.u[1] = __builtin_amdgcn_perm(q0[3], q0[2], sel);
      Aa.u[2] = __builtin_amdgcn_perm(q1[1], q1[0], sel);
      Aa.u[3] = __builtin_amdgcn_perm(q1[3], q1[2], sel);
      As[mt] = Aa.v;
      const u32x4 pw = *(const u32x4*)&PW2[t * 128 + (n0 >> 1)];
      union { bf16x8 v; unsigned int u[4]; } Pp;
      Pp.u[0] = pk2(__uint_as_float(pw[0] << 16) * sd0[0], __uint_as_float(pw[0] & 0xffff0000u) * sd0[1]);
      Pp.u[1] = pk2(__uint_as_float(pw[1] << 16) * sd0[2], __uint_as_float(pw[1] & 0xffff0000u) * sd0[3]);
      Pp.u[2] = pk2(__uint_as_float(pw[2] << 16) * sd1[0], __uint_as_float(pw[2] & 0xffff0000u) * sd1[1]);
      Pp.u[3] = pk2(__uint_as_float(pw[3] << 16) * sd1[2], __uint_as_float(pw[3] & 0xffff0000u) * sd1[3]);
      Ps[mt] = Pp.v;
    }
    #pragma unroll
    for (int ot = 0; ot < 2; ++ot) {
      const bf16x8 ctf = *(const bf16x8*)&CT[(oq * 32 + ot * 16 + l15) * NS + n0];
      #pragma unroll
      for (int mt = 0; mt < 2; ++mt) {
        yac[mt][ot] = __builtin_amdgcn_mfma_f32_16x16x32_bf16(As[mt], ctf, yac[mt][ot], 0, 0, 0);
        yac[mt][ot] = __builtin_amdgcn_mfma_f32_16x16x32_bf16(Ps[mt], ctf, yac[mt][ot], 0, 0, 0);
      }
    }
  }

  // ---- LN partials: wave covers 32 o -> exchange across oq via Lex ----
  #pragma unroll
  for (int mt = 0; mt < 2; ++mt)
    #pragma unroll
    for (int r = 0; r < 4; ++r) {
      float s1 = yac[mt][0][r] + yac[mt][1][r];
      float s2 = yac[mt][0][r] * yac[mt][0][r] + yac[mt][1][r] * yac[mt][1][r];
      #pragma unroll
      for (int d = 1; d < 16; d <<= 1) { s1 += __shfl_xor(s1, d); s2 += __shfl_xor(s2, d); }
      if (l15 == 0) {
        const int t = tt * 32 + mt * 16 + g * 4 + r;
        *(float2*)&Lexf[t * 8 + oq * 2] = make_float2(s1, s2);
      }
    }
  __syncthreads();

  // ---- LN finish + SiLU -> Hr (bf16 t-pairs, resample interleave) ----
  {
    float ga[2], be[2];
    #pragma unroll
    for (int ot = 0; ot < 2; ++ot) {
      ga[ot] = lng[oq * 32 + ot * 16 + l15];
      be[ot] = lnb[oq * 32 + ot * 16 + l15];
    }
    #pragma unroll
    for (int mt = 0; mt < 2; ++mt) {
      float mu[4], rs[4];
      #pragma unroll
      for (int r = 0; r < 4; ++r) {
        const int t = tt * 32 + mt * 16 + g * 4 + r;
        const float4 f0 = *(const float4*)&Lexf[t * 8];
        const float4 f1 = *(const float4*)&Lexf[t * 8 + 4];
        const float m = (f0.x + f0.z + f1.x + f1.z) * (1.0f / 128.0f);
        const float va = (f0.y + f0.w + f1.y + f1.w) * (1.0f / 128.0f) - m * m;
        mu[r] = m;
        rs[r] = rsqrtf(va + 1e-5f);
      }
      #pragma unroll
      for (int ot = 0; ot < 2; ++ot) {
        const int o = oq * 32 + ot * 16 + l15;
        #pragma unroll
        for (int rp = 0; rp < 2; ++rp) {
          float h0 = (yac[mt][ot][rp * 2] - mu[rp * 2]) * rs[rp * 2] * ga[ot] + be[ot];
          h0 = h0 * __builtin_amdgcn_rcpf(1.0f + __expf(-h0));
          float h1 = (yac[mt][ot][rp * 2 + 1] - mu[rp * 2 + 1]) * rs[rp * 2 + 1] * ga[ot] + be[ot];
          h1 = h1 * __builtin_amdgcn_rcpf(1.0f + __expf(-h1));
          const int t2 = tt * 16 + mt * 8 + g * 2 + rp;
          Hr[t2 * HROW + o] = pk2(h0, h1);
        }
      }
    }
  }
  __syncthreads();

  // ---- out-GEMM: wave w owns o in [16w, 16w+16); Wb lazy from L2; direct stores ----
  {
    f32x4 oac[2] = {};
    #pragma unroll
    for (int kt = 0; kt < 8; ++kt) {
      bf16x8 Aa[2];
      #pragma unroll
      for (int mt = 0; mt < 2; ++mt) {
        union { bf16x8 v; u32x4 u; } Ax;
        Ax.u = *(const u32x4*)&Hr[(mt * 16 + l15) * HROW + kt * 16 + g * 4];
        Aa[mt] = Ax.v;
      }
      const bf16x8 wf = *(const bf16x8*)&Wb[(w * 16 + l15) * NS + kt * 32 + g * 8];
      #pragma unroll
      for (int mt = 0; mt < 2; ++mt)
        oac[mt] = __builtin_amdgcn_mfma_f32_16x16x32_bf16(Aa[mt], wf, oac[mt], 0, 0, 0);
    }
    const int o = w * 16 + l15;
    const float bia = bias[o];
    #pragma unroll
    for (int mt = 0; mt < 2; ++mt) {
      float4 q;
      q.x = oac[mt][0] + bia;
      q.y = oac[mt][1] + bia;
      q.z = oac[mt][2] + bia;
      q.w = oac[mt][3] + bia;
      *(float4*)(out + ((size_t)(b * OCH + o)) * THALF + kc * 32 + mt * 16 + g * 4) = q;
    }
  }
}

// ---------------- launch ----------------
extern "C" void kernel_launch(void* const* d_in, const int* in_sizes, int n_in,
                              void* d_out, int out_size, void* d_ws, size_t ws_size,
                              hipStream_t stream) {
  const float* x    = (const float*)d_in[0];
  const float* rl   = (const float*)d_in[1];
  const float* Bc   = (const float*)d_in[2];
  const float* Cm   = (const float*)d_in[3];
  const float* lng  = (const float*)d_in[4];
  const float* lnb  = (const float*)d_in[5];
  const float* W    = (const float*)d_in[6];
  const float* bias = (const float*)d_in[7];
  float* out = (float*)d_out;

  char* ws = (char*)d_ws;
  unsigned short* BdT = (unsigned short*)(ws);            // 64 KB
  unsigned short* CT  = (unsigned short*)(ws + 65536);    // 64 KB
  unsigned short* Wb  = (unsigned short*)(ws + 131072);   // 64 KB
  float* Ad    = (float*)(ws + 196608);                   // 1 KB
  float* rL    = (float*)(ws + 197632);                   // 1 KB
  unsigned int* PW2 = (unsigned int*)(ws + 198656);       // 32 KB
  float* carry = (float*)(ws + 231424);                   // 2 MB
  unsigned int* S = (unsigned int*)(ws + 231424 + 2097152); // 64 MB (s0 scratch)

  k_prep<<<417, 256, 0, stream>>>(rl, Bc, Cm, W, BdT, CT, Wb, Ad, rL, PW2);
  k_scan<<<BATCH * NCHUNK, 512, 0, stream>>>(x, BdT, Ad, S, carry);
  k_combine<<<64, 256, 0, stream>>>(carry, rL);
  k_apply<<<BATCH * NCHUNK, 512, 0, stream>>>(S, CT, Wb, PW2, carry,
                                              lng, lnb, bias, out);
}

// Round 6
// 130.301 us; speedup vs baseline: 1.3177x; 1.3177x over previous
//
#include <hip/hip_runtime.h>

#define BATCH 8
#define CIN 128
#define OCH 128
#define T_LEN 16384
#define NS 256
#define CHUNK 64
#define NCHUNK (T_LEN / CHUNK)   // 256
#define THALF (T_LEN / 2)        // 8192
#define SCHUNK 8192              // u32 per chunk image in global: 32 rows x 256 n
#define SROW 260                 // LDS V2 row stride (u32): pad-4 -> conflict-free b128 col reads
#define HROW 132                 // Hr row stride (u32)
#define NCHK 4                   // chunks per apply block

typedef __attribute__((ext_vector_type(8))) short bf16x8;
typedef __attribute__((ext_vector_type(4))) float f32x4;
typedef __attribute__((ext_vector_type(4))) unsigned int u32x4;

__device__ __forceinline__ unsigned int pk2(float lo, float hi) {
  unsigned int d;
  asm("v_cvt_pk_bf16_f32 %0, %1, %2" : "=v"(d) : "v"(lo), "v"(hi));
  return d;
}
__device__ __forceinline__ unsigned short f2bf(float f) {
  unsigned int u = __float_as_uint(f);
  u += 0x7fffu + ((u >> 16) & 1u);
  return (unsigned short)(u >> 16);
}
__device__ __forceinline__ float softplusf_(float v) {
  return (v > 20.0f) ? v : log1pf(expf(v));
}
// barrier that does NOT drain vmcnt (keeps global prefetch in flight)
__device__ __forceinline__ void rawbar() {
  __builtin_amdgcn_sched_barrier(0);
  asm volatile("s_waitcnt lgkmcnt(0)" ::: "memory");
  __builtin_amdgcn_sched_barrier(0);
  __builtin_amdgcn_s_barrier();
  __builtin_amdgcn_sched_barrier(0);
}

// ---------------- prep: weights -> bf16, A_d, A_d^L, PWf[tp][n] = A_n^(2tp+1) ----------------
__global__ __launch_bounds__(256) void k_prep(
    const float* __restrict__ rl, const float* __restrict__ Bc,
    const float* __restrict__ Cm, const float* __restrict__ W,
    unsigned short* __restrict__ BdT, unsigned short* __restrict__ CT,
    unsigned short* __restrict__ Wb, float* __restrict__ Ad, float* __restrict__ rL,
    float* __restrict__ PWf)
{
  const int tid = blockIdx.x * 256 + threadIdx.x;
  if (tid < NS * CIN) {                       // BdT[n][c] = B_c[c][n] * (A_d-1)/lam
    const int n = tid >> 7, c = tid & 127;
    float lam = -softplusf_(rl[n]);
    float ad = expf(lam);
    float sc = (ad - 1.0f) / lam;
    BdT[tid] = f2bf(Bc[c * NS + n] * sc);
  } else if (tid < 2 * NS * CIN) {            // CT[o][n] = C[n][o]
    const int i = tid - NS * CIN;
    const int o = i >> 8, n = i & 255;
    CT[i] = f2bf(Cm[n * OCH + o]);
  } else if (tid < 3 * NS * CIN) {            // Wb[o][c2] = W[o][c2]
    const int i = tid - 2 * NS * CIN;
    Wb[i] = f2bf(W[i]);
  } else if (tid < 3 * NS * CIN + NS) {
    const int n = tid - 3 * NS * CIN;
    float lam = -softplusf_(rl[n]);
    Ad[n] = expf(lam);
    rL[n] = expf(lam * (float)CHUNK);
  } else if (tid < 3 * NS * CIN + NS + 32 * NS) {   // PWf[tp][n] = A_n^(2tp+1)
    const int i = tid - (3 * NS * CIN + NS);
    const int tp = i >> 8, n = i & 255;
    float lam = -softplusf_(rl[n]);
    PWf[i] = expf(lam * (float)(2 * tp + 1));
  }
}

// ---------------- chunk-carry combine: Hillis-Steele with multiplier A^L ----------------
__global__ __launch_bounds__(256) void k_combine(float* __restrict__ carry,
                                                 const float* __restrict__ rL)
{
  const int b = blockIdx.x >> 3;
  const int ng = blockIdx.x & 7;      // n-group of 32
  const int t = threadIdx.x;          // chunk index
  __shared__ float Y[32][NCHUNK];
  float* base = carry + ((size_t)b * NCHUNK + t) * NS + ng * 32;
  #pragma unroll
  for (int i4 = 0; i4 < 8; ++i4) {
    float4 q = *(const float4*)(base + i4 * 4);
    Y[i4 * 4 + 0][t] = q.x; Y[i4 * 4 + 1][t] = q.y;
    Y[i4 * 4 + 2][t] = q.z; Y[i4 * 4 + 3][t] = q.w;
  }
  float rp[32];
  #pragma unroll
  for (int i = 0; i < 32; ++i) rp[i] = rL[ng * 32 + i];
  __syncthreads();
  for (int d = 1; d < NCHUNK; d <<= 1) {
    float tmp[32];
    #pragma unroll
    for (int i = 0; i < 32; ++i) tmp[i] = (t >= d) ? Y[i][t - d] : 0.0f;
    __syncthreads();
    #pragma unroll
    for (int i = 0; i < 32; ++i) { Y[i][t] += rp[i] * tmp[i]; rp[i] *= rp[i]; }
    __syncthreads();
  }
  const int tm = (t == 0) ? 0 : (t - 1);
  #pragma unroll
  for (int i4 = 0; i4 < 8; ++i4) {
    float a = Y[i4 * 4 + 0][tm], bb = Y[i4 * 4 + 1][tm];
    float c = Y[i4 * 4 + 2][tm], dd = Y[i4 * 4 + 3][tm];
    float4 q;
    q.x = (t == 0) ? 0.0f : a;  q.y = (t == 0) ? 0.0f : bb;
    q.z = (t == 0) ? 0.0f : c;  q.w = (t == 0) ? 0.0f : dd;
    *(float4*)(base + i4 * 4) = q;
  }
}

// ---------------- k_scan: x -> v-GEMM -> scan(seed 0) -> s0 scratch + totals ----------------
__global__ __launch_bounds__(512, 4) void k_scan(
    const float* __restrict__ x,
    const unsigned short* __restrict__ BdT,
    const float* __restrict__ Ad,
    unsigned int* __restrict__ s0,
    float* __restrict__ carry)
{
  const int bid = blockIdx.x;
  const int b = bid >> 8;
  const int kc = bid & 255;
  const int tid = threadIdx.x;
  const int w = tid >> 6, l = tid & 63, l15 = l & 15, g = l >> 4;

  __shared__ __align__(16) unsigned int Xt[64 * 64];  // [t][c2 ^ ((t&7)<<2)] packed bf16 pairs

  // ---- stage x: thread -> (c2 = w*8 + (l&7), t-block = (l>>3)*8): contiguous 32B loads ----
  {
    const int c2 = w * 8 + (l & 7);
    const int t0b = (l >> 3) * 8;
    const float* r0 = x + ((size_t)(b * CIN + 2 * c2)) * T_LEN + kc * CHUNK + t0b;
    const f32x4 xa0 = *(const f32x4*)r0;
    const f32x4 xa1 = *(const f32x4*)(r0 + 4);
    const f32x4 xb0 = *(const f32x4*)(r0 + T_LEN);
    const f32x4 xb1 = *(const f32x4*)(r0 + T_LEN + 4);
    #pragma unroll
    for (int k = 0; k < 8; ++k) {
      const int t = t0b + k;
      const float va = (k < 4) ? xa0[k & 3] : xa1[k & 3];
      const float vb = (k < 4) ? xb0[k & 3] : xb1[k & 3];
      Xt[t * 64 + (c2 ^ ((t & 7) << 2))] = pk2(va, vb);
    }
  }

  // ---- per-wave B fragments (n in [32w, 32w+32)) + scan constants ----
  bf16x8 Bf[2][4];
  #pragma unroll
  for (int nt = 0; nt < 2; ++nt)
    #pragma unroll
    for (int kt = 0; kt < 4; ++kt)
      Bf[nt][kt] = *(const bf16x8*)&BdT[(w * 32 + nt * 16 + l15) * CIN + kt * 32 + g * 8];

  float A1[2], A2[2], A3[2], A4[2], A8[2], A16[2], A4G[2], M1[2], M2[2];
  #pragma unroll
  for (int nt = 0; nt < 2; ++nt) {
    const float a1 = Ad[w * 32 + nt * 16 + l15];
    A1[nt] = a1; A2[nt] = a1 * a1; A3[nt] = A2[nt] * a1; A4[nt] = A2[nt] * A2[nt];
    A8[nt] = A4[nt] * A4[nt]; A16[nt] = A8[nt] * A8[nt];
    float a4g = 1.0f;
    if (g & 1) a4g *= A4[nt];
    if (g & 2) a4g *= A8[nt];
    A4G[nt] = a4g;
    M1[nt] = (g >= 1) ? A4[nt] : 0.0f;
    M2[nt] = (g >= 2) ? A8[nt] : 0.0f;
  }
  __syncthreads();

  // ---- v-GEMM ----
  f32x4 vac[4][2] = {};
  #pragma unroll
  for (int kt = 0; kt < 4; ++kt) {
    bf16x8 afr[4];
    #pragma unroll
    for (int mt = 0; mt < 4; ++mt)
      afr[mt] = *(const bf16x8*)&Xt[(mt * 16 + l15) * 64 + ((kt * 16 + g * 4) ^ ((l15 & 7) << 2))];
    #pragma unroll
    for (int nt = 0; nt < 2; ++nt)
      #pragma unroll
      for (int mt = 0; mt < 4; ++mt)
        vac[mt][nt] = __builtin_amdgcn_mfma_f32_16x16x32_bf16(afr[mt], Bf[nt][kt], vac[mt][nt], 0, 0, 0);
  }

  // ---- in-register scan over t, seed 0 ----
  float crv[2];
  #pragma unroll
  for (int nt = 0; nt < 2; ++nt) {
    float cr = 0.0f;
    #pragma unroll
    for (int mt = 0; mt < 4; ++mt) {
      const float p0 = vac[mt][nt][0];
      const float p1 = fmaf(A1[nt], p0, vac[mt][nt][1]);
      const float p2 = fmaf(A1[nt], p1, vac[mt][nt][2]);
      const float p3 = fmaf(A1[nt], p2, vac[mt][nt][3]);
      float c0 = p3;
      float u = __shfl_up(c0, 16);
      c0 = fmaf(M1[nt], u, c0);
      u = __shfl_up(c0, 32);
      c0 = fmaf(M2[nt], u, c0);
      float e = __shfl_up(c0, 16);
      e = (g == 0) ? 0.0f : e;
      const float seed = fmaf(A4G[nt], cr, e);
      vac[mt][nt][0] = fmaf(A1[nt], seed, p0);
      vac[mt][nt][1] = fmaf(A2[nt], seed, p1);
      vac[mt][nt][2] = fmaf(A3[nt], seed, p2);
      vac[mt][nt][3] = fmaf(A4[nt], seed, p3);
      const float ctop = __shfl(c0, 48 + l15);
      cr = fmaf(A16[nt], cr, ctop);
    }
    crv[nt] = cr;
  }

  // ---- store packed s0 [tp][n] (linear, coalesced) + totals ----
  unsigned int* sc = s0 + (size_t)(b * NCHUNK + kc) * SCHUNK;
  #pragma unroll
  for (int mt = 0; mt < 4; ++mt)
    #pragma unroll
    for (int nt = 0; nt < 2; ++nt) {
      const int n = w * 32 + nt * 16 + l15;
      #pragma unroll
      for (int rp = 0; rp < 2; ++rp) {
        const int tp = mt * 8 + g * 2 + rp;
        sc[tp * 256 + n] = pk2(vac[mt][nt][rp * 2], vac[mt][nt][rp * 2 + 1]);
      }
    }
  if (g == 0) {
    #pragma unroll
    for (int nt = 0; nt < 2; ++nt)
      carry[((size_t)b * NCHUNK + kc) * NS + (w * 32 + nt * 16 + l15)] = crv[nt];
  }
}

// ---------------- k_apply: stage(+seed-correct) -> y-GEMM -> LN/SiLU -> out-GEMM ----------------
__global__ __launch_bounds__(512, 4) void k_apply(
    const unsigned int* __restrict__ S,
    const unsigned short* __restrict__ CT,
    const unsigned short* __restrict__ Wb,
    const float* __restrict__ PWf,
    const float* __restrict__ Ad,
    const float* __restrict__ carry,
    const float* __restrict__ lng, const float* __restrict__ lnb,
    const float* __restrict__ bias,
    float* __restrict__ out)
{
  const int bid = blockIdx.x;
  const int b = bid / (NCHUNK / NCHK);
  const int kc0 = (bid % (NCHUNK / NCHK)) * NCHK;
  const int tid = threadIdx.x;
  const int w = tid >> 6, l = tid & 63, l15 = l & 15, g = l >> 4;
  const int tt = w >> 2, oq = w & 3;

  __shared__ __align__(16) unsigned int V2[2][32 * SROW];  // 2 x 33.3 KB
  __shared__ __align__(16) float Lexf[64 * 8];             // 2 KB

  // ---- hoisted constants ----
  // correction role: thread owns rows (r*8+w), cols n = 4l..4l+3
  f32x4 pwv[4];
  #pragma unroll
  for (int r = 0; r < 4; ++r)
    pwv[r] = *(const f32x4*)&PWf[(r * 8 + w) * 256 + 4 * l];
  const f32x4 adv = *(const f32x4*)&Ad[4 * l];
  // out-GEMM weights in registers: wave owns o in [16w, 16w+16)
  bf16x8 Wf[8];
  #pragma unroll
  for (int kt = 0; kt < 8; ++kt)
    Wf[kt] = *(const bf16x8*)&Wb[(w * 16 + l15) * NS + kt * 32 + g * 8];
  float ga[2], be[2];
  #pragma unroll
  for (int ot = 0; ot < 2; ++ot) {
    ga[ot] = lng[oq * 32 + ot * 16 + l15];
    be[ot] = lnb[oq * 32 + ot * 16 + l15];
  }
  const float bia = bias[w * 16 + l15];
  const unsigned int sel = (l15 & 1) ? 0x07060302u : 0x05040100u;

  u32x4 st[4];
  f32x4 sd;
  auto correct_store = [&](unsigned int* dst) {
    #pragma unroll
    for (int r = 0; r < 4; ++r) {
      u32x4 q = st[r];
      #pragma unroll
      for (int e = 0; e < 4; ++e) {
        const float e0 = sd[e] * pwv[r][e];
        const float lo = __uint_as_float(q[e] << 16) + e0;
        const float hi = __uint_as_float(q[e] & 0xffff0000u) + e0 * adv[e];
        q[e] = pk2(lo, hi);
      }
      *(u32x4*)&dst[(r * 8 + w) * SROW + 4 * l] = q;
    }
  };

  // ---- prologue: load+correct chunk kc0 -> V2[0]; issue kc0+1 loads ----
  {
    const unsigned int* scb = S + (size_t)(b * NCHUNK + kc0) * SCHUNK;
    #pragma unroll
    for (int r = 0; r < 4; ++r) st[r] = *(const u32x4*)&scb[r * 2048 + tid * 4];
    sd = *(const f32x4*)&carry[((size_t)b * NCHUNK + kc0) * NS + 4 * l];
    correct_store(&V2[0][0]);
    const unsigned int* sc1 = S + (size_t)(b * NCHUNK + kc0 + 1) * SCHUNK;
    #pragma unroll
    for (int r = 0; r < 4; ++r) st[r] = *(const u32x4*)&sc1[r * 2048 + tid * 4];
    sd = *(const f32x4*)&carry[((size_t)b * NCHUNK + kc0 + 1) * NS + 4 * l];
  }
  rawbar();

  #pragma unroll 1
  for (int i = 0; i < NCHK; ++i) {
    const int cur = i & 1;
    const int kc = kc0 + i;

    // ---- B: y-GEMM (V2[cur] + CT from L2) + LN partials ----
    f32x4 yac[2][2] = {};
    #pragma unroll
    for (int kt = 0; kt < 8; ++kt) {
      const int n0 = kt * 32 + g * 8;
      bf16x8 As[2];
      #pragma unroll
      for (int mt = 0; mt < 2; ++mt) {
        const int tp = (tt * 32 + mt * 16 + l15) >> 1;
        const u32x4 q0 = *(const u32x4*)&V2[cur][tp * SROW + n0];
        const u32x4 q1 = *(const u32x4*)&V2[cur][tp * SROW + n0 + 4];
        union { bf16x8 v; unsigned int u[4]; } Aa;
        Aa.u[0] = __builtin_amdgcn_perm(q0[1], q0[0], sel);
        Aa.u[1] = __builtin_amdgcn_perm(q0[3], q0[2], sel);
        Aa.u[2] = __builtin_amdgcn_perm(q1[1], q1[0], sel);
        Aa.u[3] = __builtin_amdgcn_perm(q1[3], q1[2], sel);
        As[mt] = Aa.v;
      }
      #pragma unroll
      for (int ot = 0; ot < 2; ++ot) {
        const bf16x8 ctf = *(const bf16x8*)&CT[(oq * 32 + ot * 16 + l15) * NS + n0];
        #pragma unroll
        for (int mt = 0; mt < 2; ++mt)
          yac[mt][ot] = __builtin_amdgcn_mfma_f32_16x16x32_bf16(As[mt], ctf, yac[mt][ot], 0, 0, 0);
      }
    }
    #pragma unroll
    for (int mt = 0; mt < 2; ++mt)
      #pragma unroll
      for (int r = 0; r < 4; ++r) {
        float s1 = yac[mt][0][r] + yac[mt][1][r];
        float s2 = yac[mt][0][r] * yac[mt][0][r] + yac[mt][1][r] * yac[mt][1][r];
        #pragma unroll
        for (int d = 1; d < 16; d <<= 1) { s1 += __shfl_xor(s1, d); s2 += __shfl_xor(s2, d); }
        if (l15 == 0) {
          const int t = tt * 32 + mt * 16 + g * 4 + r;
          *(float2*)&Lexf[t * 8 + oq * 2] = make_float2(s1, s2);
        }
      }
    rawbar();   // C: Lex visible; V2[cur] fully read

    // ---- D: LN finish + SiLU -> Hr (aliases V2[cur]); staged correction -> V2[cur^1] ----
    unsigned int* Hr = &V2[cur][0];
    #pragma unroll
    for (int mt = 0; mt < 2; ++mt) {
      float mu[4], rs[4];
      #pragma unroll
      for (int r = 0; r < 4; ++r) {
        const int t = tt * 32 + mt * 16 + g * 4 + r;
        const float4 f0 = *(const float4*)&Lexf[t * 8];
        const float4 f1 = *(const float4*)&Lexf[t * 8 + 4];
        const float m = (f0.x + f0.z + f1.x + f1.z) * (1.0f / 128.0f);
        const float va = (f0.y + f0.w + f1.y + f1.w) * (1.0f / 128.0f) - m * m;
        mu[r] = m;
        rs[r] = rsqrtf(va + 1e-5f);
      }
      #pragma unroll
      for (int ot = 0; ot < 2; ++ot) {
        const int o = oq * 32 + ot * 16 + l15;
        #pragma unroll
        for (int rp = 0; rp < 2; ++rp) {
          float h0 = (yac[mt][ot][rp * 2] - mu[rp * 2]) * rs[rp * 2] * ga[ot] + be[ot];
          h0 = h0 * __builtin_amdgcn_rcpf(1.0f + __expf(-h0));
          float h1 = (yac[mt][ot][rp * 2 + 1] - mu[rp * 2 + 1]) * rs[rp * 2 + 1] * ga[ot] + be[ot];
          h1 = h1 * __builtin_amdgcn_rcpf(1.0f + __expf(-h1));
          const int t2 = tt * 16 + mt * 8 + g * 2 + rp;
          Hr[t2 * HROW + o] = pk2(h0, h1);
        }
      }
    }
    if (i + 1 < NCHK) {
      correct_store(&V2[cur ^ 1][0]);   // compiler inserts vmcnt wait on st here
      if (i + 2 < NCHK) {
        const unsigned int* sc2 = S + (size_t)(b * NCHUNK + kc + 2) * SCHUNK;
        #pragma unroll
        for (int r = 0; r < 4; ++r) st[r] = *(const u32x4*)&sc2[r * 2048 + tid * 4];
        sd = *(const f32x4*)&carry[((size_t)b * NCHUNK + kc + 2) * NS + 4 * l];
      }
    }
    rawbar();   // E: Hr + next-chunk stage visible

    // ---- F: out-GEMM (Hr + Wf regs) -> direct stores ----
    {
      f32x4 oac[2] = {};
      #pragma unroll
      for (int kt = 0; kt < 8; ++kt) {
        bf16x8 Aa[2];
        #pragma unroll
        for (int mt = 0; mt < 2; ++mt) {
          union { bf16x8 v; u32x4 u; } Ax;
          Ax.u = *(const u32x4*)&Hr[(mt * 16 + l15) * HROW + kt * 16 + g * 4];
          Aa[mt] = Ax.v;
        }
        #pragma unroll
        for (int mt = 0; mt < 2; ++mt)
          oac[mt] = __builtin_amdgcn_mfma_f32_16x16x32_bf16(Aa[mt], Wf[kt], oac[mt], 0, 0, 0);
      }
      const int o = w * 16 + l15;
      #pragma unroll
      for (int mt = 0; mt < 2; ++mt) {
        float4 q;
        q.x = oac[mt][0] + bia;
        q.y = oac[mt][1] + bia;
        q.z = oac[mt][2] + bia;
        q.w = oac[mt][3] + bia;
        *(float4*)(out + ((size_t)(b * OCH + o)) * THALF + kc * 32 + mt * 16 + g * 4) = q;
      }
    }
  }
}

// ---------------- launch ----------------
extern "C" void kernel_launch(void* const* d_in, const int* in_sizes, int n_in,
                              void* d_out, int out_size, void* d_ws, size_t ws_size,
                              hipStream_t stream) {
  const float* x    = (const float*)d_in[0];
  const float* rl   = (const float*)d_in[1];
  const float* Bc   = (const float*)d_in[2];
  const float* Cm   = (const float*)d_in[3];
  const float* lng  = (const float*)d_in[4];
  const float* lnb  = (const float*)d_in[5];
  const float* W    = (const float*)d_in[6];
  const float* bias = (const float*)d_in[7];
  float* out = (float*)d_out;

  char* ws = (char*)d_ws;
  unsigned short* BdT = (unsigned short*)(ws);            // 64 KB
  unsigned short* CT  = (unsigned short*)(ws + 65536);    // 64 KB
  unsigned short* Wb  = (unsigned short*)(ws + 131072);   // 64 KB
  float* Ad    = (float*)(ws + 196608);                   // 1 KB
  float* rL    = (float*)(ws + 197632);                   // 1 KB
  float* PWf   = (float*)(ws + 198656);                   // 32 KB
  float* carry = (float*)(ws + 231424);                   // 2 MB
  unsigned int* S = (unsigned int*)(ws + 231424 + 2097152); // 64 MB

  k_prep<<<417, 256, 0, stream>>>(rl, Bc, Cm, W, BdT, CT, Wb, Ad, rL, PWf);
  k_scan<<<BATCH * NCHUNK, 512, 0, stream>>>(x, BdT, Ad, S, carry);
  k_combine<<<64, 256, 0, stream>>>(carry, rL);
  k_apply<<<BATCH * (NCHUNK / NCHK), 512, 0, stream>>>(S, CT, Wb, PWf, Ad, carry,
                                                       lng, lnb, bias, out);
}

// Round 7
// 124.064 us; speedup vs baseline: 1.3840x; 1.0503x over previous
//
#include <hip/hip_runtime.h>

#define BATCH 8
#define CIN 128
#define OCH 128
#define T_LEN 16384
#define NS 256
#define CHUNK 64
#define NCHUNK (T_LEN / CHUNK)   // 256
#define THALF (T_LEN / 2)        // 8192
#define SCHUNK 8192              // u32 per chunk image in global: 32 rows x 256 n
#define SROW 260                 // LDS V2 row stride (u32)
#define HROW 132                 // Hr row stride (u32)
#define NCHK 4                   // chunks per apply block

typedef __attribute__((ext_vector_type(8))) short bf16x8;
typedef __attribute__((ext_vector_type(4))) float f32x4;
typedef __attribute__((ext_vector_type(4))) unsigned int u32x4;

__device__ __forceinline__ unsigned int pk2(float lo, float hi) {
  unsigned int d;
  asm("v_cvt_pk_bf16_f32 %0, %1, %2" : "=v"(d) : "v"(lo), "v"(hi));
  return d;
}
__device__ __forceinline__ unsigned short f2bf(float f) {
  unsigned int u = __float_as_uint(f);
  u += 0x7fffu + ((u >> 16) & 1u);
  return (unsigned short)(u >> 16);
}
__device__ __forceinline__ float softplusf_(float v) {
  return (v > 20.0f) ? v : log1pf(expf(v));
}
// barrier that does NOT drain vmcnt (keeps global prefetch in flight)
__device__ __forceinline__ void rawbar() {
  __builtin_amdgcn_sched_barrier(0);
  asm volatile("s_waitcnt lgkmcnt(0)" ::: "memory");
  __builtin_amdgcn_sched_barrier(0);
  __builtin_amdgcn_s_barrier();
  __builtin_amdgcn_sched_barrier(0);
}

// ---------------- prep: weights -> bf16, A_d, A_d^L, PWf[tp][n] = A_n^(2tp+1) ----------------
__global__ __launch_bounds__(256) void k_prep(
    const float* __restrict__ rl, const float* __restrict__ Bc,
    const float* __restrict__ Cm, const float* __restrict__ W,
    unsigned short* __restrict__ BdT, unsigned short* __restrict__ CT,
    unsigned short* __restrict__ Wb, float* __restrict__ Ad, float* __restrict__ rL,
    float* __restrict__ PWf)
{
  const int tid = blockIdx.x * 256 + threadIdx.x;
  if (tid < NS * CIN) {                       // BdT[n][c] = B_c[c][n] * (A_d-1)/lam
    const int n = tid >> 7, c = tid & 127;
    float lam = -softplusf_(rl[n]);
    float ad = expf(lam);
    float sc = (ad - 1.0f) / lam;
    BdT[tid] = f2bf(Bc[c * NS + n] * sc);
  } else if (tid < 2 * NS * CIN) {            // CT[o][n] = C[n][o]
    const int i = tid - NS * CIN;
    const int o = i >> 8, n = i & 255;
    CT[i] = f2bf(Cm[n * OCH + o]);
  } else if (tid < 3 * NS * CIN) {            // Wb[o][c2] = W[o][c2]
    const int i = tid - 2 * NS * CIN;
    Wb[i] = f2bf(W[i]);
  } else if (tid < 3 * NS * CIN + NS) {
    const int n = tid - 3 * NS * CIN;
    float lam = -softplusf_(rl[n]);
    Ad[n] = expf(lam);
    rL[n] = expf(lam * (float)CHUNK);
  } else if (tid < 3 * NS * CIN + NS + 32 * NS) {   // PWf[tp][n] = A_n^(2tp+1)
    const int i = tid - (3 * NS * CIN + NS);
    const int tp = i >> 8, n = i & 255;
    float lam = -softplusf_(rl[n]);
    PWf[i] = expf(lam * (float)(2 * tp + 1));
  }
}

// ---------------- chunk-carry combine: Hillis-Steele with multiplier A^L ----------------
__global__ __launch_bounds__(256) void k_combine(float* __restrict__ carry,
                                                 const float* __restrict__ rL)
{
  const int b = blockIdx.x >> 3;
  const int ng = blockIdx.x & 7;      // n-group of 32
  const int t = threadIdx.x;          // chunk index
  __shared__ float Y[32][NCHUNK];
  float* base = carry + ((size_t)b * NCHUNK + t) * NS + ng * 32;
  #pragma unroll
  for (int i4 = 0; i4 < 8; ++i4) {
    float4 q = *(const float4*)(base + i4 * 4);
    Y[i4 * 4 + 0][t] = q.x; Y[i4 * 4 + 1][t] = q.y;
    Y[i4 * 4 + 2][t] = q.z; Y[i4 * 4 + 3][t] = q.w;
  }
  float rp[32];
  #pragma unroll
  for (int i = 0; i < 32; ++i) rp[i] = rL[ng * 32 + i];
  __syncthreads();
  for (int d = 1; d < NCHUNK; d <<= 1) {
    float tmp[32];
    #pragma unroll
    for (int i = 0; i < 32; ++i) tmp[i] = (t >= d) ? Y[i][t - d] : 0.0f;
    __syncthreads();
    #pragma unroll
    for (int i = 0; i < 32; ++i) { Y[i][t] += rp[i] * tmp[i]; rp[i] *= rp[i]; }
    __syncthreads();
  }
  const int tm = (t == 0) ? 0 : (t - 1);
  #pragma unroll
  for (int i4 = 0; i4 < 8; ++i4) {
    float a = Y[i4 * 4 + 0][tm], bb = Y[i4 * 4 + 1][tm];
    float c = Y[i4 * 4 + 2][tm], dd = Y[i4 * 4 + 3][tm];
    float4 q;
    q.x = (t == 0) ? 0.0f : a;  q.y = (t == 0) ? 0.0f : bb;
    q.z = (t == 0) ? 0.0f : c;  q.w = (t == 0) ? 0.0f : dd;
    *(float4*)(base + i4 * 4) = q;
  }
}

// ---------------- k_scan: x -> v-GEMM -> scan(seed 0) -> s0 scratch + totals ----------------
__global__ __launch_bounds__(512, 4) void k_scan(
    const float* __restrict__ x,
    const unsigned short* __restrict__ BdT,
    const float* __restrict__ Ad,
    unsigned int* __restrict__ s0,
    float* __restrict__ carry)
{
  const int bid = blockIdx.x;
  const int b = bid >> 8;
  const int kc = bid & 255;
  const int tid = threadIdx.x;
  const int w = tid >> 6, l = tid & 63, l15 = l & 15, g = l >> 4;

  __shared__ __align__(16) unsigned int Xt[64 * 64];  // [t][c2 ^ ((t&7)<<2)] packed bf16 pairs

  // ---- stage x: thread -> (c2 = w*8 + (l&7), t-block = (l>>3)*8): contiguous 32B loads ----
  {
    const int c2 = w * 8 + (l & 7);
    const int t0b = (l >> 3) * 8;
    const float* r0 = x + ((size_t)(b * CIN + 2 * c2)) * T_LEN + kc * CHUNK + t0b;
    const f32x4 xa0 = *(const f32x4*)r0;
    const f32x4 xa1 = *(const f32x4*)(r0 + 4);
    const f32x4 xb0 = *(const f32x4*)(r0 + T_LEN);
    const f32x4 xb1 = *(const f32x4*)(r0 + T_LEN + 4);
    #pragma unroll
    for (int k = 0; k < 8; ++k) {
      const int t = t0b + k;
      const float va = (k < 4) ? xa0[k & 3] : xa1[k & 3];
      const float vb = (k < 4) ? xb0[k & 3] : xb1[k & 3];
      Xt[t * 64 + (c2 ^ ((t & 7) << 2))] = pk2(va, vb);
    }
  }

  // ---- per-wave B fragments (n in [32w, 32w+32)) + scan constants ----
  bf16x8 Bf[2][4];
  #pragma unroll
  for (int nt = 0; nt < 2; ++nt)
    #pragma unroll
    for (int kt = 0; kt < 4; ++kt)
      Bf[nt][kt] = *(const bf16x8*)&BdT[(w * 32 + nt * 16 + l15) * CIN + kt * 32 + g * 8];

  float A1[2], A2[2], A3[2], A4[2], A8[2], A16[2], A4G[2], M1[2], M2[2];
  #pragma unroll
  for (int nt = 0; nt < 2; ++nt) {
    const float a1 = Ad[w * 32 + nt * 16 + l15];
    A1[nt] = a1; A2[nt] = a1 * a1; A3[nt] = A2[nt] * a1; A4[nt] = A2[nt] * A2[nt];
    A8[nt] = A4[nt] * A4[nt]; A16[nt] = A8[nt] * A8[nt];
    float a4g = 1.0f;
    if (g & 1) a4g *= A4[nt];
    if (g & 2) a4g *= A8[nt];
    A4G[nt] = a4g;
    M1[nt] = (g >= 1) ? A4[nt] : 0.0f;
    M2[nt] = (g >= 2) ? A8[nt] : 0.0f;
  }
  __syncthreads();

  // ---- v-GEMM ----
  f32x4 vac[4][2] = {};
  #pragma unroll
  for (int kt = 0; kt < 4; ++kt) {
    bf16x8 afr[4];
    #pragma unroll
    for (int mt = 0; mt < 4; ++mt)
      afr[mt] = *(const bf16x8*)&Xt[(mt * 16 + l15) * 64 + ((kt * 16 + g * 4) ^ ((l15 & 7) << 2))];
    #pragma unroll
    for (int nt = 0; nt < 2; ++nt)
      #pragma unroll
      for (int mt = 0; mt < 4; ++mt)
        vac[mt][nt] = __builtin_amdgcn_mfma_f32_16x16x32_bf16(afr[mt], Bf[nt][kt], vac[mt][nt], 0, 0, 0);
  }

  // ---- in-register scan over t, seed 0 ----
  float crv[2];
  #pragma unroll
  for (int nt = 0; nt < 2; ++nt) {
    float cr = 0.0f;
    #pragma unroll
    for (int mt = 0; mt < 4; ++mt) {
      const float p0 = vac[mt][nt][0];
      const float p1 = fmaf(A1[nt], p0, vac[mt][nt][1]);
      const float p2 = fmaf(A1[nt], p1, vac[mt][nt][2]);
      const float p3 = fmaf(A1[nt], p2, vac[mt][nt][3]);
      float c0 = p3;
      float u = __shfl_up(c0, 16);
      c0 = fmaf(M1[nt], u, c0);
      u = __shfl_up(c0, 32);
      c0 = fmaf(M2[nt], u, c0);
      float e = __shfl_up(c0, 16);
      e = (g == 0) ? 0.0f : e;
      const float seed = fmaf(A4G[nt], cr, e);
      vac[mt][nt][0] = fmaf(A1[nt], seed, p0);
      vac[mt][nt][1] = fmaf(A2[nt], seed, p1);
      vac[mt][nt][2] = fmaf(A3[nt], seed, p2);
      vac[mt][nt][3] = fmaf(A4[nt], seed, p3);
      const float ctop = __shfl(c0, 48 + l15);
      cr = fmaf(A16[nt], cr, ctop);
    }
    crv[nt] = cr;
  }

  // ---- store packed s0 [tp][n] (linear, coalesced) + totals ----
  unsigned int* sc = s0 + (size_t)(b * NCHUNK + kc) * SCHUNK;
  #pragma unroll
  for (int mt = 0; mt < 4; ++mt)
    #pragma unroll
    for (int nt = 0; nt < 2; ++nt) {
      const int n = w * 32 + nt * 16 + l15;
      #pragma unroll
      for (int rp = 0; rp < 2; ++rp) {
        const int tp = mt * 8 + g * 2 + rp;
        sc[tp * 256 + n] = pk2(vac[mt][nt][rp * 2], vac[mt][nt][rp * 2 + 1]);
      }
    }
  if (g == 0) {
    #pragma unroll
    for (int nt = 0; nt < 2; ++nt)
      carry[((size_t)b * NCHUNK + kc) * NS + (w * 32 + nt * 16 + l15)] = crv[nt];
  }
}

// ---------------- k_apply: stage(+seed-correct) -> y-GEMM -> LN/SiLU -> out-GEMM ----------------
// No lambdas, no long-lived hand-hoisted weight arrays: loop-invariant loads are
// written at their use site so LICM can hoist them only if registers allow.
__global__ __launch_bounds__(512, 4) void k_apply(
    const unsigned int* __restrict__ S,
    const unsigned short* __restrict__ CT,
    const unsigned short* __restrict__ Wb,
    const float* __restrict__ PWf,
    const float* __restrict__ Ad,
    const float* __restrict__ carry,
    const float* __restrict__ lng, const float* __restrict__ lnb,
    const float* __restrict__ bias,
    float* __restrict__ out)
{
  const int bid = blockIdx.x;
  const int b = bid / (NCHUNK / NCHK);
  const int kc0 = (bid % (NCHUNK / NCHK)) * NCHK;
  const int tid = threadIdx.x;
  const int w = tid >> 6, l = tid & 63, l15 = l & 15, g = l >> 4;
  const int tt = w >> 2, oq = w & 3;

  __shared__ __align__(16) unsigned int V2[2][32 * SROW];  // 2 x 33.3 KB
  __shared__ __align__(16) float Lexf[64 * 8];             // 2 KB

  const unsigned int sel = (l15 & 1) ? 0x07060302u : 0x05040100u;
  const f32x4 adv = *(const f32x4*)&Ad[4 * l];

  u32x4 st0, st1, st2, st3;
  f32x4 sd;

#define LOAD_ST(KC) do {                                                    \
    const unsigned int* scb_ = S + (size_t)(b * NCHUNK + (KC)) * SCHUNK;    \
    st0 = *(const u32x4*)&scb_[0 * 2048 + tid * 4];                         \
    st1 = *(const u32x4*)&scb_[1 * 2048 + tid * 4];                         \
    st2 = *(const u32x4*)&scb_[2 * 2048 + tid * 4];                         \
    st3 = *(const u32x4*)&scb_[3 * 2048 + tid * 4];                         \
    sd  = *(const f32x4*)&carry[((size_t)b * NCHUNK + (KC)) * NS + 4 * l];  \
  } while (0)

#define CORRECT_ROW(QV, RR) do {                                            \
    const f32x4 pw_ = *(const f32x4*)&PWf[((RR) * 8 + w) * 256 + 4 * l];    \
    const float e00 = sd[0] * pw_[0];                                       \
    const float e01 = sd[1] * pw_[1];                                       \
    const float e02 = sd[2] * pw_[2];                                       \
    const float e03 = sd[3] * pw_[3];                                       \
    QV[0] = pk2(__uint_as_float(QV[0] << 16) + e00,                         \
                __uint_as_float(QV[0] & 0xffff0000u) + e00 * adv[0]);       \
    QV[1] = pk2(__uint_as_float(QV[1] << 16) + e01,                         \
                __uint_as_float(QV[1] & 0xffff0000u) + e01 * adv[1]);       \
    QV[2] = pk2(__uint_as_float(QV[2] << 16) + e02,                         \
                __uint_as_float(QV[2] & 0xffff0000u) + e02 * adv[2]);       \
    QV[3] = pk2(__uint_as_float(QV[3] << 16) + e03,                         \
                __uint_as_float(QV[3] & 0xffff0000u) + e03 * adv[3]);       \
    *(u32x4*)&dst_[((RR) * 8 + w) * SROW + 4 * l] = QV;                     \
  } while (0)

#define CORRECT_STORE(DST) do {                                             \
    unsigned int* dst_ = (DST);                                             \
    CORRECT_ROW(st0, 0);                                                    \
    CORRECT_ROW(st1, 1);                                                    \
    CORRECT_ROW(st2, 2);                                                    \
    CORRECT_ROW(st3, 3);                                                    \
  } while (0)

  // ---- prologue: load+correct chunk kc0 -> V2[0]; issue kc0+1 loads ----
  LOAD_ST(kc0);
  CORRECT_STORE(&V2[0][0]);
  LOAD_ST(kc0 + 1);
  rawbar();

  #pragma unroll 1
  for (int i = 0; i < NCHK; ++i) {
    const int cur = i & 1;
    const int kc = kc0 + i;

    // ---- B: y-GEMM (V2[cur] from LDS, CT from L2) + LN partials ----
    f32x4 yac[2][2] = {};
    #pragma unroll
    for (int kt = 0; kt < 8; ++kt) {
      const int n0 = kt * 32 + g * 8;
      bf16x8 As[2];
      #pragma unroll
      for (int mt = 0; mt < 2; ++mt) {
        const int tp = (tt * 32 + mt * 16 + l15) >> 1;
        const u32x4 q0 = *(const u32x4*)&V2[cur][tp * SROW + n0];
        const u32x4 q1 = *(const u32x4*)&V2[cur][tp * SROW + n0 + 4];
        union { bf16x8 v; unsigned int u[4]; } Aa;
        Aa.u[0] = __builtin_amdgcn_perm(q0[1], q0[0], sel);
        Aa.u[1] = __builtin_amdgcn_perm(q0[3], q0[2], sel);
        Aa.u[2] = __builtin_amdgcn_perm(q1[1], q1[0], sel);
        Aa.u[3] = __builtin_amdgcn_perm(q1[3], q1[2], sel);
        As[mt] = Aa.v;
      }
      #pragma unroll
      for (int ot = 0; ot < 2; ++ot) {
        const bf16x8 ctf = *(const bf16x8*)&CT[(oq * 32 + ot * 16 + l15) * NS + n0];
        #pragma unroll
        for (int mt = 0; mt < 2; ++mt)
          yac[mt][ot] = __builtin_amdgcn_mfma_f32_16x16x32_bf16(As[mt], ctf, yac[mt][ot], 0, 0, 0);
      }
    }
    #pragma unroll
    for (int mt = 0; mt < 2; ++mt)
      #pragma unroll
      for (int r = 0; r < 4; ++r) {
        float s1 = yac[mt][0][r] + yac[mt][1][r];
        float s2 = yac[mt][0][r] * yac[mt][0][r] + yac[mt][1][r] * yac[mt][1][r];
        #pragma unroll
        for (int d = 1; d < 16; d <<= 1) { s1 += __shfl_xor(s1, d); s2 += __shfl_xor(s2, d); }
        if (l15 == 0) {
          const int t = tt * 32 + mt * 16 + g * 4 + r;
          *(float2*)&Lexf[t * 8 + oq * 2] = make_float2(s1, s2);
        }
      }
    rawbar();   // C: Lex visible; V2[cur] fully read

    // ---- D: LN finish + SiLU -> Hr (aliases V2[cur]); staged correction -> V2[cur^1] ----
    unsigned int* Hr = &V2[cur][0];
    #pragma unroll
    for (int mt = 0; mt < 2; ++mt) {
      float mu[4], rs[4];
      #pragma unroll
      for (int r = 0; r < 4; ++r) {
        const int t = tt * 32 + mt * 16 + g * 4 + r;
        const float4 f0 = *(const float4*)&Lexf[t * 8];
        const float4 f1 = *(const float4*)&Lexf[t * 8 + 4];
        const float m = (f0.x + f0.z + f1.x + f1.z) * (1.0f / 128.0f);
        const float va = (f0.y + f0.w + f1.y + f1.w) * (1.0f / 128.0f) - m * m;
        mu[r] = m;
        rs[r] = rsqrtf(va + 1e-5f);
      }
      const float ga0 = lng[oq * 32 + l15],      be0 = lnb[oq * 32 + l15];
      const float ga1 = lng[oq * 32 + 16 + l15], be1 = lnb[oq * 32 + 16 + l15];
      #pragma unroll
      for (int ot = 0; ot < 2; ++ot) {
        const int o = oq * 32 + ot * 16 + l15;
        const float ga = ot ? ga1 : ga0;
        const float be = ot ? be1 : be0;
        #pragma unroll
        for (int rp = 0; rp < 2; ++rp) {
          float h0 = (yac[mt][ot][rp * 2] - mu[rp * 2]) * rs[rp * 2] * ga + be;
          h0 = h0 * __builtin_amdgcn_rcpf(1.0f + __expf(-h0));
          float h1 = (yac[mt][ot][rp * 2 + 1] - mu[rp * 2 + 1]) * rs[rp * 2 + 1] * ga + be;
          h1 = h1 * __builtin_amdgcn_rcpf(1.0f + __expf(-h1));
          const int t2 = tt * 16 + mt * 8 + g * 2 + rp;
          Hr[t2 * HROW + o] = pk2(h0, h1);
        }
      }
    }
    if (i + 1 < NCHK) {
      CORRECT_STORE(&V2[cur ^ 1][0]);   // compiler inserts vmcnt wait on st here
      if (i + 2 < NCHK) LOAD_ST(kc + 2);
    }
    rawbar();   // E: Hr + next-chunk stage visible

    // ---- F: out-GEMM (Hr from LDS, Wb from L2) -> direct stores ----
    {
      f32x4 oac[2] = {};
      #pragma unroll
      for (int kt = 0; kt < 8; ++kt) {
        bf16x8 Aa0, Aa1;
        {
          union { bf16x8 v; u32x4 u; } Ax;
          Ax.u = *(const u32x4*)&Hr[(l15) * HROW + kt * 16 + g * 4];
          Aa0 = Ax.v;
          Ax.u = *(const u32x4*)&Hr[(16 + l15) * HROW + kt * 16 + g * 4];
          Aa1 = Ax.v;
        }
        const bf16x8 wf = *(const bf16x8*)&Wb[(w * 16 + l15) * NS + kt * 32 + g * 8];
        oac[0] = __builtin_amdgcn_mfma_f32_16x16x32_bf16(Aa0, wf, oac[0], 0, 0, 0);
        oac[1] = __builtin_amdgcn_mfma_f32_16x16x32_bf16(Aa1, wf, oac[1], 0, 0, 0);
      }
      const int o = w * 16 + l15;
      const float bia = bias[o];
      #pragma unroll
      for (int mt = 0; mt < 2; ++mt) {
        float4 q;
        q.x = oac[mt][0] + bia;
        q.y = oac[mt][1] + bia;
        q.z = oac[mt][2] + bia;
        q.w = oac[mt][3] + bia;
        *(float4*)(out + ((size_t)(b * OCH + o)) * THALF + kc * 32 + mt * 16 + g * 4) = q;
      }
    }
  }
#undef LOAD_ST
#undef CORRECT_ROW
#undef CORRECT_STORE
}

// ---------------- launch ----------------
extern "C" void kernel_launch(void* const* d_in, const int* in_sizes, int n_in,
                              void* d_out, int out_size, void* d_ws, size_t ws_size,
                              hipStream_t stream) {
  const float* x    = (const float*)d_in[0];
  const float* rl   = (const float*)d_in[1];
  const float* Bc   = (const float*)d_in[2];
  const float* Cm   = (const float*)d_in[3];
  const float* lng  = (const float*)d_in[4];
  const float* lnb  = (const float*)d_in[5];
  const float* W    = (const float*)d_in[6];
  const float* bias = (const float*)d_in[7];
  float* out = (float*)d_out;

  char* ws = (char*)d_ws;
  unsigned short* BdT = (unsigned short*)(ws);            // 64 KB
  unsigned short* CT  = (unsigned short*)(ws + 65536);    // 64 KB
  unsigned short* Wb  = (unsigned short*)(ws + 131072);   // 64 KB
  float* Ad    = (float*)(ws + 196608);                   // 1 KB
  float* rL    = (float*)(ws + 197632);                   // 1 KB
  float* PWf   = (float*)(ws + 198656);                   // 32 KB
  float* carry = (float*)(ws + 231424);                   // 2 MB
  unsigned int* S = (unsigned int*)(ws + 231424 + 2097152); // 64 MB

  k_prep<<<417, 256, 0, stream>>>(rl, Bc, Cm, W, BdT, CT, Wb, Ad, rL, PWf);
  k_scan<<<BATCH * NCHUNK, 512, 0, stream>>>(x, BdT, Ad, S, carry);
  k_combine<<<64, 256, 0, stream>>>(carry, rL);
  k_apply<<<BATCH * (NCHUNK / NCHK), 512, 0, stream>>>(S, CT, Wb, PWf, Ad, carry,
                                                       lng, lnb, bias, out);
}

// Round 8
// 115.345 us; speedup vs baseline: 1.4886x; 1.0756x over previous
//
#include <hip/hip_runtime.h>

#define BATCH 8
#define CIN 128
#define OCH 128
#define T_LEN 16384
#define NS 256
#define CHUNK 64
#define NCHUNK (T_LEN / CHUNK)   // 256
#define THALF (T_LEN / 2)        // 8192
#define SCHUNK 8192              // u32 per chunk image in global: 32 rows x 256 n
#define SROW 260                 // LDS V2 row stride (u32)
#define HROW 132                 // Hr row stride (u32)
#define NCHK 4                   // chunks per apply block

typedef __attribute__((ext_vector_type(8))) short bf16x8;
typedef __attribute__((ext_vector_type(4))) float f32x4;
typedef __attribute__((ext_vector_type(4))) unsigned int u32x4;

__device__ __forceinline__ unsigned int pk2(float lo, float hi) {
  unsigned int d;
  asm("v_cvt_pk_bf16_f32 %0, %1, %2" : "=v"(d) : "v"(lo), "v"(hi));
  return d;
}
__device__ __forceinline__ unsigned short f2bf(float f) {
  unsigned int u = __float_as_uint(f);
  u += 0x7fffu + ((u >> 16) & 1u);
  return (unsigned short)(u >> 16);
}
__device__ __forceinline__ float softplusf_(float v) {
  return (v > 20.0f) ? v : log1pf(expf(v));
}
// barrier that does NOT drain vmcnt (keeps global prefetch in flight)
__device__ __forceinline__ void rawbar() {
  __builtin_amdgcn_sched_barrier(0);
  asm volatile("s_waitcnt lgkmcnt(0)" ::: "memory");
  __builtin_amdgcn_sched_barrier(0);
  __builtin_amdgcn_s_barrier();
  __builtin_amdgcn_sched_barrier(0);
}

// ---------------- prep: weights -> bf16, A_d, A_d^L, PWf[tp][n] = A_n^(2tp+1) ----------------
__global__ __launch_bounds__(256) void k_prep(
    const float* __restrict__ rl, const float* __restrict__ Bc,
    const float* __restrict__ Cm, const float* __restrict__ W,
    unsigned short* __restrict__ BdT, unsigned short* __restrict__ CT,
    unsigned short* __restrict__ Wb, float* __restrict__ Ad, float* __restrict__ rL,
    float* __restrict__ PWf)
{
  const int tid = blockIdx.x * 256 + threadIdx.x;
  if (tid < NS * CIN) {                       // BdT[n][c] = B_c[c][n] * (A_d-1)/lam
    const int n = tid >> 7, c = tid & 127;
    float lam = -softplusf_(rl[n]);
    float ad = expf(lam);
    float sc = (ad - 1.0f) / lam;
    BdT[tid] = f2bf(Bc[c * NS + n] * sc);
  } else if (tid < 2 * NS * CIN) {            // CT[o][n] = C[n][o]
    const int i = tid - NS * CIN;
    const int o = i >> 8, n = i & 255;
    CT[i] = f2bf(Cm[n * OCH + o]);
  } else if (tid < 3 * NS * CIN) {            // Wb[o][c2] = W[o][c2]
    const int i = tid - 2 * NS * CIN;
    Wb[i] = f2bf(W[i]);
  } else if (tid < 3 * NS * CIN + NS) {
    const int n = tid - 3 * NS * CIN;
    float lam = -softplusf_(rl[n]);
    Ad[n] = expf(lam);
    rL[n] = expf(lam * (float)CHUNK);
  } else if (tid < 3 * NS * CIN + NS + 32 * NS) {   // PWf[tp][n] = A_n^(2tp+1)
    const int i = tid - (3 * NS * CIN + NS);
    const int tp = i >> 8, n = i & 255;
    float lam = -softplusf_(rl[n]);
    PWf[i] = expf(lam * (float)(2 * tp + 1));
  }
}

// ---------------- chunk-carry combine: Hillis-Steele with multiplier A^L ----------------
__global__ __launch_bounds__(256) void k_combine(float* __restrict__ carry,
                                                 const float* __restrict__ rL)
{
  const int b = blockIdx.x >> 3;
  const int ng = blockIdx.x & 7;      // n-group of 32
  const int t = threadIdx.x;          // chunk index
  __shared__ float Y[32][NCHUNK];
  float* base = carry + ((size_t)b * NCHUNK + t) * NS + ng * 32;
  #pragma unroll
  for (int i4 = 0; i4 < 8; ++i4) {
    float4 q = *(const float4*)(base + i4 * 4);
    Y[i4 * 4 + 0][t] = q.x; Y[i4 * 4 + 1][t] = q.y;
    Y[i4 * 4 + 2][t] = q.z; Y[i4 * 4 + 3][t] = q.w;
  }
  float rp[32];
  #pragma unroll
  for (int i = 0; i < 32; ++i) rp[i] = rL[ng * 32 + i];
  __syncthreads();
  for (int d = 1; d < NCHUNK; d <<= 1) {
    float tmp[32];
    #pragma unroll
    for (int i = 0; i < 32; ++i) tmp[i] = (t >= d) ? Y[i][t - d] : 0.0f;
    __syncthreads();
    #pragma unroll
    for (int i = 0; i < 32; ++i) { Y[i][t] += rp[i] * tmp[i]; rp[i] *= rp[i]; }
    __syncthreads();
  }
  const int tm = (t == 0) ? 0 : (t - 1);
  #pragma unroll
  for (int i4 = 0; i4 < 8; ++i4) {
    float a = Y[i4 * 4 + 0][tm], bb = Y[i4 * 4 + 1][tm];
    float c = Y[i4 * 4 + 2][tm], dd = Y[i4 * 4 + 3][tm];
    float4 q;
    q.x = (t == 0) ? 0.0f : a;  q.y = (t == 0) ? 0.0f : bb;
    q.z = (t == 0) ? 0.0f : c;  q.w = (t == 0) ? 0.0f : dd;
    *(float4*)(base + i4 * 4) = q;
  }
}

// ---------------- k_scan: x -> v-GEMM -> scan(seed 0) -> s0 scratch + totals ----------------
__global__ __launch_bounds__(512, 4) void k_scan(
    const float* __restrict__ x,
    const unsigned short* __restrict__ BdT,
    const float* __restrict__ Ad,
    unsigned int* __restrict__ s0,
    float* __restrict__ carry)
{
  const int bid = blockIdx.x;
  const int b = bid >> 8;
  const int kc = bid & 255;
  const int tid = threadIdx.x;
  const int w = tid >> 6, l = tid & 63, l15 = l & 15, g = l >> 4;

  __shared__ __align__(16) unsigned int Xt[64 * 64];  // [t][c2 ^ ((t&7)<<2)] packed bf16 pairs

  // ---- stage x: thread -> (c2 = w*8 + (l&7), t-block = (l>>3)*8): contiguous 32B loads ----
  {
    const int c2 = w * 8 + (l & 7);
    const int t0b = (l >> 3) * 8;
    const float* r0 = x + ((size_t)(b * CIN + 2 * c2)) * T_LEN + kc * CHUNK + t0b;
    const f32x4 xa0 = *(const f32x4*)r0;
    const f32x4 xa1 = *(const f32x4*)(r0 + 4);
    const f32x4 xb0 = *(const f32x4*)(r0 + T_LEN);
    const f32x4 xb1 = *(const f32x4*)(r0 + T_LEN + 4);
    #pragma unroll
    for (int k = 0; k < 8; ++k) {
      const int t = t0b + k;
      const float va = (k < 4) ? xa0[k & 3] : xa1[k & 3];
      const float vb = (k < 4) ? xb0[k & 3] : xb1[k & 3];
      Xt[t * 64 + (c2 ^ ((t & 7) << 2))] = pk2(va, vb);
    }
  }

  // ---- per-wave B fragments (n in [32w, 32w+32)) + scan constants ----
  bf16x8 Bf[2][4];
  #pragma unroll
  for (int nt = 0; nt < 2; ++nt)
    #pragma unroll
    for (int kt = 0; kt < 4; ++kt)
      Bf[nt][kt] = *(const bf16x8*)&BdT[(w * 32 + nt * 16 + l15) * CIN + kt * 32 + g * 8];

  float A1[2], A2[2], A3[2], A4[2], A8[2], A16[2], A4G[2], M1[2], M2[2];
  #pragma unroll
  for (int nt = 0; nt < 2; ++nt) {
    const float a1 = Ad[w * 32 + nt * 16 + l15];
    A1[nt] = a1; A2[nt] = a1 * a1; A3[nt] = A2[nt] * a1; A4[nt] = A2[nt] * A2[nt];
    A8[nt] = A4[nt] * A4[nt]; A16[nt] = A8[nt] * A8[nt];
    float a4g = 1.0f;
    if (g & 1) a4g *= A4[nt];
    if (g & 2) a4g *= A8[nt];
    A4G[nt] = a4g;
    M1[nt] = (g >= 1) ? A4[nt] : 0.0f;
    M2[nt] = (g >= 2) ? A8[nt] : 0.0f;
  }
  __syncthreads();

  // ---- v-GEMM ----
  f32x4 vac[4][2] = {};
  #pragma unroll
  for (int kt = 0; kt < 4; ++kt) {
    bf16x8 afr[4];
    #pragma unroll
    for (int mt = 0; mt < 4; ++mt)
      afr[mt] = *(const bf16x8*)&Xt[(mt * 16 + l15) * 64 + ((kt * 16 + g * 4) ^ ((l15 & 7) << 2))];
    #pragma unroll
    for (int nt = 0; nt < 2; ++nt)
      #pragma unroll
      for (int mt = 0; mt < 4; ++mt)
        vac[mt][nt] = __builtin_amdgcn_mfma_f32_16x16x32_bf16(afr[mt], Bf[nt][kt], vac[mt][nt], 0, 0, 0);
  }

  // ---- in-register scan over t, seed 0 ----
  float crv[2];
  #pragma unroll
  for (int nt = 0; nt < 2; ++nt) {
    float cr = 0.0f;
    #pragma unroll
    for (int mt = 0; mt < 4; ++mt) {
      const float p0 = vac[mt][nt][0];
      const float p1 = fmaf(A1[nt], p0, vac[mt][nt][1]);
      const float p2 = fmaf(A1[nt], p1, vac[mt][nt][2]);
      const float p3 = fmaf(A1[nt], p2, vac[mt][nt][3]);
      float c0 = p3;
      float u = __shfl_up(c0, 16);
      c0 = fmaf(M1[nt], u, c0);
      u = __shfl_up(c0, 32);
      c0 = fmaf(M2[nt], u, c0);
      float e = __shfl_up(c0, 16);
      e = (g == 0) ? 0.0f : e;
      const float seed = fmaf(A4G[nt], cr, e);
      vac[mt][nt][0] = fmaf(A1[nt], seed, p0);
      vac[mt][nt][1] = fmaf(A2[nt], seed, p1);
      vac[mt][nt][2] = fmaf(A3[nt], seed, p2);
      vac[mt][nt][3] = fmaf(A4[nt], seed, p3);
      const float ctop = __shfl(c0, 48 + l15);
      cr = fmaf(A16[nt], cr, ctop);
    }
    crv[nt] = cr;
  }

  // ---- store packed s0 [tp][n] (linear, coalesced) + totals ----
  unsigned int* sc = s0 + (size_t)(b * NCHUNK + kc) * SCHUNK;
  #pragma unroll
  for (int mt = 0; mt < 4; ++mt)
    #pragma unroll
    for (int nt = 0; nt < 2; ++nt) {
      const int n = w * 32 + nt * 16 + l15;
      #pragma unroll
      for (int rp = 0; rp < 2; ++rp) {
        const int tp = mt * 8 + g * 2 + rp;
        sc[tp * 256 + n] = pk2(vac[mt][nt][rp * 2], vac[mt][nt][rp * 2 + 1]);
      }
    }
  if (g == 0) {
    #pragma unroll
    for (int nt = 0; nt < 2; ++nt)
      carry[((size_t)b * NCHUNK + kc) * NS + (w * 32 + nt * 16 + l15)] = crv[nt];
  }
}

// ---------------- k_apply: stage(+seed-correct) -> y-GEMM -> LN/SiLU -> out-GEMM ----------------
// LDS caps occupancy at 2 blocks/CU, so declare exactly that: (512, 2) -> 256-VGPR cap.
// R7's (512,4) made the allocator spill the staging registers to scratch (~120 MB/dispatch).
__global__ __launch_bounds__(512, 2) void k_apply(
    const unsigned int* __restrict__ S,
    const unsigned short* __restrict__ CT,
    const unsigned short* __restrict__ Wb,
    const float* __restrict__ PWf,
    const float* __restrict__ Ad,
    const float* __restrict__ carry,
    const float* __restrict__ lng, const float* __restrict__ lnb,
    const float* __restrict__ bias,
    float* __restrict__ out)
{
  const int bid = blockIdx.x;
  const int b = bid / (NCHUNK / NCHK);
  const int kc0 = (bid % (NCHUNK / NCHK)) * NCHK;
  const int tid = threadIdx.x;
  const int w = tid >> 6, l = tid & 63, l15 = l & 15, g = l >> 4;
  const int tt = w >> 2, oq = w & 3;

  __shared__ __align__(16) unsigned int V2[2][32 * SROW];  // 2 x 33.3 KB
  __shared__ __align__(16) float Lexf[64 * 8];             // 2 KB

  const unsigned int sel = (l15 & 1) ? 0x07060302u : 0x05040100u;
  const f32x4 adv = *(const f32x4*)&Ad[4 * l];

  u32x4 st0, st1, st2, st3;
  f32x4 sd;

#define LOAD_ST(KC) do {                                                    \
    const unsigned int* scb_ = S + (size_t)(b * NCHUNK + (KC)) * SCHUNK;    \
    st0 = *(const u32x4*)&scb_[0 * 2048 + tid * 4];                         \
    st1 = *(const u32x4*)&scb_[1 * 2048 + tid * 4];                         \
    st2 = *(const u32x4*)&scb_[2 * 2048 + tid * 4];                         \
    st3 = *(const u32x4*)&scb_[3 * 2048 + tid * 4];                         \
    sd  = *(const f32x4*)&carry[((size_t)b * NCHUNK + (KC)) * NS + 4 * l];  \
  } while (0)

#define CORRECT_ROW(QV, RR) do {                                            \
    const f32x4 pw_ = *(const f32x4*)&PWf[((RR) * 8 + w) * 256 + 4 * l];    \
    const float e00 = sd[0] * pw_[0];                                       \
    const float e01 = sd[1] * pw_[1];                                       \
    const float e02 = sd[2] * pw_[2];                                       \
    const float e03 = sd[3] * pw_[3];                                       \
    QV[0] = pk2(__uint_as_float(QV[0] << 16) + e00,                         \
                __uint_as_float(QV[0] & 0xffff0000u) + e00 * adv[0]);       \
    QV[1] = pk2(__uint_as_float(QV[1] << 16) + e01,                         \
                __uint_as_float(QV[1] & 0xffff0000u) + e01 * adv[1]);       \
    QV[2] = pk2(__uint_as_float(QV[2] << 16) + e02,                         \
                __uint_as_float(QV[2] & 0xffff0000u) + e02 * adv[2]);       \
    QV[3] = pk2(__uint_as_float(QV[3] << 16) + e03,                         \
                __uint_as_float(QV[3] & 0xffff0000u) + e03 * adv[3]);       \
    *(u32x4*)&dst_[((RR) * 8 + w) * SROW + 4 * l] = QV;                     \
  } while (0)

#define CORRECT_STORE(DST) do {                                             \
    unsigned int* dst_ = (DST);                                             \
    CORRECT_ROW(st0, 0);                                                    \
    CORRECT_ROW(st1, 1);                                                    \
    CORRECT_ROW(st2, 2);                                                    \
    CORRECT_ROW(st3, 3);                                                    \
  } while (0)

  // ---- prologue: load+correct chunk kc0 -> V2[0]; issue kc0+1 loads ----
  LOAD_ST(kc0);
  CORRECT_STORE(&V2[0][0]);
  LOAD_ST(kc0 + 1);
  rawbar();

  #pragma unroll 1
  for (int i = 0; i < NCHK; ++i) {
    const int cur = i & 1;
    const int kc = kc0 + i;

    // ---- B: y-GEMM (V2[cur] from LDS, CT from L2) + LN partials ----
    f32x4 yac[2][2] = {};
    #pragma unroll
    for (int kt = 0; kt < 8; ++kt) {
      const int n0 = kt * 32 + g * 8;
      bf16x8 As[2];
      #pragma unroll
      for (int mt = 0; mt < 2; ++mt) {
        const int tp = (tt * 32 + mt * 16 + l15) >> 1;
        const u32x4 q0 = *(const u32x4*)&V2[cur][tp * SROW + n0];
        const u32x4 q1 = *(const u32x4*)&V2[cur][tp * SROW + n0 + 4];
        union { bf16x8 v; unsigned int u[4]; } Aa;
        Aa.u[0] = __builtin_amdgcn_perm(q0[1], q0[0], sel);
        Aa.u[1] = __builtin_amdgcn_perm(q0[3], q0[2], sel);
        Aa.u[2] = __builtin_amdgcn_perm(q1[1], q1[0], sel);
        Aa.u[3] = __builtin_amdgcn_perm(q1[3], q1[2], sel);
        As[mt] = Aa.v;
      }
      #pragma unroll
      for (int ot = 0; ot < 2; ++ot) {
        const bf16x8 ctf = *(const bf16x8*)&CT[(oq * 32 + ot * 16 + l15) * NS + n0];
        #pragma unroll
        for (int mt = 0; mt < 2; ++mt)
          yac[mt][ot] = __builtin_amdgcn_mfma_f32_16x16x32_bf16(As[mt], ctf, yac[mt][ot], 0, 0, 0);
      }
    }
    #pragma unroll
    for (int mt = 0; mt < 2; ++mt)
      #pragma unroll
      for (int r = 0; r < 4; ++r) {
        float s1 = yac[mt][0][r] + yac[mt][1][r];
        float s2 = yac[mt][0][r] * yac[mt][0][r] + yac[mt][1][r] * yac[mt][1][r];
        #pragma unroll
        for (int d = 1; d < 16; d <<= 1) { s1 += __shfl_xor(s1, d); s2 += __shfl_xor(s2, d); }
        if (l15 == 0) {
          const int t = tt * 32 + mt * 16 + g * 4 + r;
          *(float2*)&Lexf[t * 8 + oq * 2] = make_float2(s1, s2);
        }
      }
    rawbar();   // C: Lex visible; V2[cur] fully read

    // ---- D: LN finish + SiLU -> Hr (aliases V2[cur]); staged correction -> V2[cur^1] ----
    unsigned int* Hr = &V2[cur][0];
    #pragma unroll
    for (int mt = 0; mt < 2; ++mt) {
      float mu[4], rs[4];
      #pragma unroll
      for (int r = 0; r < 4; ++r) {
        const int t = tt * 32 + mt * 16 + g * 4 + r;
        const float4 f0 = *(const float4*)&Lexf[t * 8];
        const float4 f1 = *(const float4*)&Lexf[t * 8 + 4];
        const float m = (f0.x + f0.z + f1.x + f1.z) * (1.0f / 128.0f);
        const float va = (f0.y + f0.w + f1.y + f1.w) * (1.0f / 128.0f) - m * m;
        mu[r] = m;
        rs[r] = rsqrtf(va + 1e-5f);
      }
      const float ga0 = lng[oq * 32 + l15],      be0 = lnb[oq * 32 + l15];
      const float ga1 = lng[oq * 32 + 16 + l15], be1 = lnb[oq * 32 + 16 + l15];
      #pragma unroll
      for (int ot = 0; ot < 2; ++ot) {
        const int o = oq * 32 + ot * 16 + l15;
        const float ga = ot ? ga1 : ga0;
        const float be = ot ? be1 : be0;
        #pragma unroll
        for (int rp = 0; rp < 2; ++rp) {
          float h0 = (yac[mt][ot][rp * 2] - mu[rp * 2]) * rs[rp * 2] * ga + be;
          h0 = h0 * __builtin_amdgcn_rcpf(1.0f + __expf(-h0));
          float h1 = (yac[mt][ot][rp * 2 + 1] - mu[rp * 2 + 1]) * rs[rp * 2 + 1] * ga + be;
          h1 = h1 * __builtin_amdgcn_rcpf(1.0f + __expf(-h1));
          const int t2 = tt * 16 + mt * 8 + g * 2 + rp;
          Hr[t2 * HROW + o] = pk2(h0, h1);
        }
      }
    }
    if (i + 1 < NCHK) {
      CORRECT_STORE(&V2[cur ^ 1][0]);   // compiler inserts vmcnt wait on st here
      if (i + 2 < NCHK) LOAD_ST(kc + 2);
    }
    rawbar();   // E: Hr + next-chunk stage visible

    // ---- F: out-GEMM (Hr from LDS, Wb from L2) -> direct stores ----
    {
      f32x4 oac[2] = {};
      #pragma unroll
      for (int kt = 0; kt < 8; ++kt) {
        bf16x8 Aa0, Aa1;
        {
          union { bf16x8 v; u32x4 u; } Ax;
          Ax.u = *(const u32x4*)&Hr[(l15) * HROW + kt * 16 + g * 4];
          Aa0 = Ax.v;
          Ax.u = *(const u32x4*)&Hr[(16 + l15) * HROW + kt * 16 + g * 4];
          Aa1 = Ax.v;
        }
        const bf16x8 wf = *(const bf16x8*)&Wb[(w * 16 + l15) * NS + kt * 32 + g * 8];
        oac[0] = __builtin_amdgcn_mfma_f32_16x16x32_bf16(Aa0, wf, oac[0], 0, 0, 0);
        oac[1] = __builtin_amdgcn_mfma_f32_16x16x32_bf16(Aa1, wf, oac[1], 0, 0, 0);
      }
      const int o = w * 16 + l15;
      const float bia = bias[o];
      #pragma unroll
      for (int mt = 0; mt < 2; ++mt) {
        float4 q;
        q.x = oac[mt][0] + bia;
        q.y = oac[mt][1] + bia;
        q.z = oac[mt][2] + bia;
        q.w = oac[mt][3] + bia;
        *(float4*)(out + ((size_t)(b * OCH + o)) * THALF + kc * 32 + mt * 16 + g * 4) = q;
      }
    }
  }
#undef LOAD_ST
#undef CORRECT_ROW
#undef CORRECT_STORE
}

// ---------------- launch ----------------
extern "C" void kernel_launch(void* const* d_in, const int* in_sizes, int n_in,
                              void* d_out, int out_size, void* d_ws, size_t ws_size,
                              hipStream_t stream) {
  const float* x    = (const float*)d_in[0];
  const float* rl   = (const float*)d_in[1];
  const float* Bc   = (const float*)d_in[2];
  const float* Cm   = (const float*)d_in[3];
  const float* lng  = (const float*)d_in[4];
  const float* lnb  = (const float*)d_in[5];
  const float* W    = (const float*)d_in[6];
  const float* bias = (const float*)d_in[7];
  float* out = (float*)d_out;

  char* ws = (char*)d_ws;
  unsigned short* BdT = (unsigned short*)(ws);            // 64 KB
  unsigned short* CT  = (unsigned short*)(ws + 65536);    // 64 KB
  unsigned short* Wb  = (unsigned short*)(ws + 131072);   // 64 KB
  float* Ad    = (float*)(ws + 196608);                   // 1 KB
  float* rL    = (float*)(ws + 197632);                   // 1 KB
  float* PWf   = (float*)(ws + 198656);                   // 32 KB
  float* carry = (float*)(ws + 231424);                   // 2 MB
  unsigned int* S = (unsigned int*)(ws + 231424 + 2097152); // 64 MB

  k_prep<<<417, 256, 0, stream>>>(rl, Bc, Cm, W, BdT, CT, Wb, Ad, rL, PWf);
  k_scan<<<BATCH * NCHUNK, 512, 0, stream>>>(x, BdT, Ad, S, carry);
  k_combine<<<64, 256, 0, stream>>>(carry, rL);
  k_apply<<<BATCH * (NCHUNK / NCHK), 512, 0, stream>>>(S, CT, Wb, PWf, Ad, carry,
                                                       lng, lnb, bias, out);
}

// Round 9
// 104.537 us; speedup vs baseline: 1.6425x; 1.1034x over previous
//
#include <hip/hip_runtime.h>

#define BATCH 8
#define CIN 128
#define OCH 128
#define T_LEN 16384
#define NS 256
#define CHUNK 64
#define NCHUNK (T_LEN / CHUNK)   // 256
#define THALF (T_LEN / 2)        // 8192
#define SCHUNK 8192              // u32 per chunk image in global: 32 rows x 256 n
#define SROW 260                 // LDS V2 row stride (u32)
#define HROW 132                 // Hr row stride (u32)
#define NCHK 4                   // chunks per apply block

typedef __attribute__((ext_vector_type(8))) short bf16x8;
typedef __attribute__((ext_vector_type(4))) float f32x4;
typedef __attribute__((ext_vector_type(4))) unsigned int u32x4;

__device__ __forceinline__ unsigned int pk2(float lo, float hi) {
  unsigned int d;
  asm("v_cvt_pk_bf16_f32 %0, %1, %2" : "=v"(d) : "v"(lo), "v"(hi));
  return d;
}
__device__ __forceinline__ unsigned short f2bf(float f) {
  unsigned int u = __float_as_uint(f);
  u += 0x7fffu + ((u >> 16) & 1u);
  return (unsigned short)(u >> 16);
}
__device__ __forceinline__ float softplusf_(float v) {
  return (v > 20.0f) ? v : log1pf(expf(v));
}
// barrier that does NOT drain vmcnt (keeps global prefetch in flight)
__device__ __forceinline__ void rawbar() {
  __builtin_amdgcn_sched_barrier(0);
  asm volatile("s_waitcnt lgkmcnt(0)" ::: "memory");
  __builtin_amdgcn_sched_barrier(0);
  __builtin_amdgcn_s_barrier();
  __builtin_amdgcn_sched_barrier(0);
}

// ---------------- prep: weights -> bf16, A_d, A_d^L, PWf[tp][n] = A_n^(2tp+1) ----------------
__global__ __launch_bounds__(256) void k_prep(
    const float* __restrict__ rl, const float* __restrict__ Bc,
    const float* __restrict__ Cm, const float* __restrict__ W,
    unsigned short* __restrict__ BdT, unsigned short* __restrict__ CT,
    unsigned short* __restrict__ Wb, float* __restrict__ Ad, float* __restrict__ rL,
    float* __restrict__ PWf)
{
  const int tid = blockIdx.x * 256 + threadIdx.x;
  if (tid < NS * CIN) {                       // BdT[n][c] = B_c[c][n] * (A_d-1)/lam
    const int n = tid >> 7, c = tid & 127;
    float lam = -softplusf_(rl[n]);
    float ad = expf(lam);
    float sc = (ad - 1.0f) / lam;
    BdT[tid] = f2bf(Bc[c * NS + n] * sc);
  } else if (tid < 2 * NS * CIN) {            // CT[o][n] = C[n][o]
    const int i = tid - NS * CIN;
    const int o = i >> 8, n = i & 255;
    CT[i] = f2bf(Cm[n * OCH + o]);
  } else if (tid < 3 * NS * CIN) {            // Wb[o][c2] = W[o][c2]
    const int i = tid - 2 * NS * CIN;
    Wb[i] = f2bf(W[i]);
  } else if (tid < 3 * NS * CIN + NS) {
    const int n = tid - 3 * NS * CIN;
    float lam = -softplusf_(rl[n]);
    Ad[n] = expf(lam);
    rL[n] = expf(lam * (float)CHUNK);
  } else if (tid < 3 * NS * CIN + NS + 32 * NS) {   // PWf[tp][n] = A_n^(2tp+1)
    const int i = tid - (3 * NS * CIN + NS);
    const int tp = i >> 8, n = i & 255;
    float lam = -softplusf_(rl[n]);
    PWf[i] = expf(lam * (float)(2 * tp + 1));
  }
}

// ---------------- chunk-carry combine: Hillis-Steele with multiplier A^L ----------------
__global__ __launch_bounds__(256) void k_combine(float* __restrict__ carry,
                                                 const float* __restrict__ rL)
{
  const int b = blockIdx.x >> 3;
  const int ng = blockIdx.x & 7;      // n-group of 32
  const int t = threadIdx.x;          // chunk index
  __shared__ float Y[32][NCHUNK];
  float* base = carry + ((size_t)b * NCHUNK + t) * NS + ng * 32;
  #pragma unroll
  for (int i4 = 0; i4 < 8; ++i4) {
    float4 q = *(const float4*)(base + i4 * 4);
    Y[i4 * 4 + 0][t] = q.x; Y[i4 * 4 + 1][t] = q.y;
    Y[i4 * 4 + 2][t] = q.z; Y[i4 * 4 + 3][t] = q.w;
  }
  float rp[32];
  #pragma unroll
  for (int i = 0; i < 32; ++i) rp[i] = rL[ng * 32 + i];
  __syncthreads();
  for (int d = 1; d < NCHUNK; d <<= 1) {
    float tmp[32];
    #pragma unroll
    for (int i = 0; i < 32; ++i) tmp[i] = (t >= d) ? Y[i][t - d] : 0.0f;
    __syncthreads();
    #pragma unroll
    for (int i = 0; i < 32; ++i) { Y[i][t] += rp[i] * tmp[i]; rp[i] *= rp[i]; }
    __syncthreads();
  }
  const int tm = (t == 0) ? 0 : (t - 1);
  #pragma unroll
  for (int i4 = 0; i4 < 8; ++i4) {
    float a = Y[i4 * 4 + 0][tm], bb = Y[i4 * 4 + 1][tm];
    float c = Y[i4 * 4 + 2][tm], dd = Y[i4 * 4 + 3][tm];
    float4 q;
    q.x = (t == 0) ? 0.0f : a;  q.y = (t == 0) ? 0.0f : bb;
    q.z = (t == 0) ? 0.0f : c;  q.w = (t == 0) ? 0.0f : dd;
    *(float4*)(base + i4 * 4) = q;
  }
}

// ---------------- k_scan: x -> v-GEMM -> scan(seed 0) -> s0 scratch + totals ----------------
__global__ __launch_bounds__(512, 4) void k_scan(
    const float* __restrict__ x,
    const unsigned short* __restrict__ BdT,
    const float* __restrict__ Ad,
    unsigned int* __restrict__ s0,
    float* __restrict__ carry)
{
  const int bid = blockIdx.x;
  const int b = bid >> 8;
  const int kc = bid & 255;
  const int tid = threadIdx.x;
  const int w = tid >> 6, l = tid & 63, l15 = l & 15, g = l >> 4;

  __shared__ __align__(16) unsigned int Xt[64 * 64];  // [t][c2 ^ ((t&7)<<2)] packed bf16 pairs

  // ---- stage x: thread -> (c2 = w*8 + (l&7), t-block = (l>>3)*8): contiguous 32B loads ----
  {
    const int c2 = w * 8 + (l & 7);
    const int t0b = (l >> 3) * 8;
    const float* r0 = x + ((size_t)(b * CIN + 2 * c2)) * T_LEN + kc * CHUNK + t0b;
    const f32x4 xa0 = *(const f32x4*)r0;
    const f32x4 xa1 = *(const f32x4*)(r0 + 4);
    const f32x4 xb0 = *(const f32x4*)(r0 + T_LEN);
    const f32x4 xb1 = *(const f32x4*)(r0 + T_LEN + 4);
    #pragma unroll
    for (int k = 0; k < 8; ++k) {
      const int t = t0b + k;
      const float va = (k < 4) ? xa0[k & 3] : xa1[k & 3];
      const float vb = (k < 4) ? xb0[k & 3] : xb1[k & 3];
      Xt[t * 64 + (c2 ^ ((t & 7) << 2))] = pk2(va, vb);
    }
  }

  // ---- per-wave B fragments (n in [32w, 32w+32)) + scan constants ----
  bf16x8 Bf[2][4];
  #pragma unroll
  for (int nt = 0; nt < 2; ++nt)
    #pragma unroll
    for (int kt = 0; kt < 4; ++kt)
      Bf[nt][kt] = *(const bf16x8*)&BdT[(w * 32 + nt * 16 + l15) * CIN + kt * 32 + g * 8];

  float A1[2], A2[2], A3[2], A4[2], A8[2], A16[2], A4G[2], M1[2], M2[2];
  #pragma unroll
  for (int nt = 0; nt < 2; ++nt) {
    const float a1 = Ad[w * 32 + nt * 16 + l15];
    A1[nt] = a1; A2[nt] = a1 * a1; A3[nt] = A2[nt] * a1; A4[nt] = A2[nt] * A2[nt];
    A8[nt] = A4[nt] * A4[nt]; A16[nt] = A8[nt] * A8[nt];
    float a4g = 1.0f;
    if (g & 1) a4g *= A4[nt];
    if (g & 2) a4g *= A8[nt];
    A4G[nt] = a4g;
    M1[nt] = (g >= 1) ? A4[nt] : 0.0f;
    M2[nt] = (g >= 2) ? A8[nt] : 0.0f;
  }
  __syncthreads();

  // ---- v-GEMM ----
  f32x4 vac[4][2] = {};
  #pragma unroll
  for (int kt = 0; kt < 4; ++kt) {
    bf16x8 afr[4];
    #pragma unroll
    for (int mt = 0; mt < 4; ++mt)
      afr[mt] = *(const bf16x8*)&Xt[(mt * 16 + l15) * 64 + ((kt * 16 + g * 4) ^ ((l15 & 7) << 2))];
    #pragma unroll
    for (int nt = 0; nt < 2; ++nt)
      #pragma unroll
      for (int mt = 0; mt < 4; ++mt)
        vac[mt][nt] = __builtin_amdgcn_mfma_f32_16x16x32_bf16(afr[mt], Bf[nt][kt], vac[mt][nt], 0, 0, 0);
  }

  // ---- in-register scan over t, seed 0 ----
  float crv[2];
  #pragma unroll
  for (int nt = 0; nt < 2; ++nt) {
    float cr = 0.0f;
    #pragma unroll
    for (int mt = 0; mt < 4; ++mt) {
      const float p0 = vac[mt][nt][0];
      const float p1 = fmaf(A1[nt], p0, vac[mt][nt][1]);
      const float p2 = fmaf(A1[nt], p1, vac[mt][nt][2]);
      const float p3 = fmaf(A1[nt], p2, vac[mt][nt][3]);
      float c0 = p3;
      float u = __shfl_up(c0, 16);
      c0 = fmaf(M1[nt], u, c0);
      u = __shfl_up(c0, 32);
      c0 = fmaf(M2[nt], u, c0);
      float e = __shfl_up(c0, 16);
      e = (g == 0) ? 0.0f : e;
      const float seed = fmaf(A4G[nt], cr, e);
      vac[mt][nt][0] = fmaf(A1[nt], seed, p0);
      vac[mt][nt][1] = fmaf(A2[nt], seed, p1);
      vac[mt][nt][2] = fmaf(A3[nt], seed, p2);
      vac[mt][nt][3] = fmaf(A4[nt], seed, p3);
      const float ctop = __shfl(c0, 48 + l15);
      cr = fmaf(A16[nt], cr, ctop);
    }
    crv[nt] = cr;
  }

  // ---- store packed s0 [tp][n] (linear, coalesced) + totals ----
  unsigned int* sc = s0 + (size_t)(b * NCHUNK + kc) * SCHUNK;
  #pragma unroll
  for (int mt = 0; mt < 4; ++mt)
    #pragma unroll
    for (int nt = 0; nt < 2; ++nt) {
      const int n = w * 32 + nt * 16 + l15;
      #pragma unroll
      for (int rp = 0; rp < 2; ++rp) {
        const int tp = mt * 8 + g * 2 + rp;
        sc[tp * 256 + n] = pk2(vac[mt][nt][rp * 2], vac[mt][nt][rp * 2 + 1]);
      }
    }
  if (g == 0) {
    #pragma unroll
    for (int nt = 0; nt < 2; ++nt)
      carry[((size_t)b * NCHUNK + kc) * NS + (w * 32 + nt * 16 + l15)] = crv[nt];
  }
}

// ---------------- k_apply: stage(+seed-correct) -> y-GEMM -> LN/SiLU -> out-GEMM ----------------
// LDS caps occupancy at 2 blocks/CU -> (512,2). Weight slices (CT, Wb) live in REGISTERS,
// loaded once per block: kills the per-chunk L2 gather streaming (~1 GB/dispatch in R8).
__global__ __launch_bounds__(512, 2) void k_apply(
    const unsigned int* __restrict__ S,
    const unsigned short* __restrict__ CT,
    const unsigned short* __restrict__ Wb,
    const float* __restrict__ PWf,
    const float* __restrict__ Ad,
    const float* __restrict__ carry,
    const float* __restrict__ lng, const float* __restrict__ lnb,
    const float* __restrict__ bias,
    float* __restrict__ out)
{
  const int bid = blockIdx.x;
  const int b = bid / (NCHUNK / NCHK);
  const int kc0 = (bid % (NCHUNK / NCHK)) * NCHK;
  const int tid = threadIdx.x;
  const int w = tid >> 6, l = tid & 63, l15 = l & 15, g = l >> 4;
  const int tt = w >> 2, oq = w & 3;

  __shared__ __align__(16) unsigned int V2[2][32 * SROW];  // 2 x 33.3 KB
  __shared__ __align__(16) float Lexf[64 * 8];             // 2 KB

  const unsigned int sel = (l15 & 1) ? 0x07060302u : 0x05040100u;
  const f32x4 adv = *(const f32x4*)&Ad[4 * l];

  // ---- loop-invariant weight fragments in registers (loaded ONCE per block) ----
  bf16x8 ctf[8][2];
  #pragma unroll
  for (int kt = 0; kt < 8; ++kt)
    #pragma unroll
    for (int ot = 0; ot < 2; ++ot)
      ctf[kt][ot] = *(const bf16x8*)&CT[(oq * 32 + ot * 16 + l15) * NS + kt * 32 + g * 8];
  bf16x8 wf[8];
  #pragma unroll
  for (int kt = 0; kt < 8; ++kt)
    wf[kt] = *(const bf16x8*)&Wb[(w * 16 + l15) * NS + kt * 32 + g * 8];
  const float ga0 = lng[oq * 32 + l15],      be0 = lnb[oq * 32 + l15];
  const float ga1 = lng[oq * 32 + 16 + l15], be1 = lnb[oq * 32 + 16 + l15];
  const float bia = bias[w * 16 + l15];

  u32x4 st0, st1, st2, st3;
  f32x4 sd;

#define LOAD_ST(KC) do {                                                    \
    const unsigned int* scb_ = S + (size_t)(b * NCHUNK + (KC)) * SCHUNK;    \
    st0 = *(const u32x4*)&scb_[0 * 2048 + tid * 4];                         \
    st1 = *(const u32x4*)&scb_[1 * 2048 + tid * 4];                         \
    st2 = *(const u32x4*)&scb_[2 * 2048 + tid * 4];                         \
    st3 = *(const u32x4*)&scb_[3 * 2048 + tid * 4];                         \
    sd  = *(const f32x4*)&carry[((size_t)b * NCHUNK + (KC)) * NS + 4 * l];  \
  } while (0)

#define CORRECT_ROW(QV, RR) do {                                            \
    const f32x4 pw_ = *(const f32x4*)&PWf[((RR) * 8 + w) * 256 + 4 * l];    \
    const float e00 = sd[0] * pw_[0];                                       \
    const float e01 = sd[1] * pw_[1];                                       \
    const float e02 = sd[2] * pw_[2];                                       \
    const float e03 = sd[3] * pw_[3];                                       \
    QV[0] = pk2(__uint_as_float(QV[0] << 16) + e00,                         \
                __uint_as_float(QV[0] & 0xffff0000u) + e00 * adv[0]);       \
    QV[1] = pk2(__uint_as_float(QV[1] << 16) + e01,                         \
                __uint_as_float(QV[1] & 0xffff0000u) + e01 * adv[1]);       \
    QV[2] = pk2(__uint_as_float(QV[2] << 16) + e02,                         \
                __uint_as_float(QV[2] & 0xffff0000u) + e02 * adv[2]);       \
    QV[3] = pk2(__uint_as_float(QV[3] << 16) + e03,                         \
                __uint_as_float(QV[3] & 0xffff0000u) + e03 * adv[3]);       \
    *(u32x4*)&dst_[((RR) * 8 + w) * SROW + 4 * l] = QV;                     \
  } while (0)

#define CORRECT_STORE(DST) do {                                             \
    unsigned int* dst_ = (DST);                                             \
    CORRECT_ROW(st0, 0);                                                    \
    CORRECT_ROW(st1, 1);                                                    \
    CORRECT_ROW(st2, 2);                                                    \
    CORRECT_ROW(st3, 3);                                                    \
  } while (0)

  // ---- prologue: load+correct chunk kc0 -> V2[0]; issue kc0+1 loads ----
  LOAD_ST(kc0);
  CORRECT_STORE(&V2[0][0]);
  LOAD_ST(kc0 + 1);
  rawbar();

  #pragma unroll 1
  for (int i = 0; i < NCHK; ++i) {
    const int cur = i & 1;
    const int kc = kc0 + i;

    // ---- B: y-GEMM (V2[cur] from LDS, CT from regs) + LN partials ----
    f32x4 yac[2][2] = {};
    #pragma unroll
    for (int kt = 0; kt < 8; ++kt) {
      const int n0 = kt * 32 + g * 8;
      bf16x8 As[2];
      #pragma unroll
      for (int mt = 0; mt < 2; ++mt) {
        const int tp = (tt * 32 + mt * 16 + l15) >> 1;
        const u32x4 q0 = *(const u32x4*)&V2[cur][tp * SROW + n0];
        const u32x4 q1 = *(const u32x4*)&V2[cur][tp * SROW + n0 + 4];
        union { bf16x8 v; unsigned int u[4]; } Aa;
        Aa.u[0] = __builtin_amdgcn_perm(q0[1], q0[0], sel);
        Aa.u[1] = __builtin_amdgcn_perm(q0[3], q0[2], sel);
        Aa.u[2] = __builtin_amdgcn_perm(q1[1], q1[0], sel);
        Aa.u[3] = __builtin_amdgcn_perm(q1[3], q1[2], sel);
        As[mt] = Aa.v;
      }
      #pragma unroll
      for (int ot = 0; ot < 2; ++ot)
        #pragma unroll
        for (int mt = 0; mt < 2; ++mt)
          yac[mt][ot] = __builtin_amdgcn_mfma_f32_16x16x32_bf16(As[mt], ctf[kt][ot], yac[mt][ot], 0, 0, 0);
    }
    #pragma unroll
    for (int mt = 0; mt < 2; ++mt)
      #pragma unroll
      for (int r = 0; r < 4; ++r) {
        float s1 = yac[mt][0][r] + yac[mt][1][r];
        float s2 = yac[mt][0][r] * yac[mt][0][r] + yac[mt][1][r] * yac[mt][1][r];
        #pragma unroll
        for (int d = 1; d < 16; d <<= 1) { s1 += __shfl_xor(s1, d); s2 += __shfl_xor(s2, d); }
        if (l15 == 0) {
          const int t = tt * 32 + mt * 16 + g * 4 + r;
          *(float2*)&Lexf[t * 8 + oq * 2] = make_float2(s1, s2);
        }
      }
    rawbar();   // C: Lex visible; V2[cur] fully read

    // ---- D: LN finish + SiLU -> Hr (aliases V2[cur]); staged correction -> V2[cur^1] ----
    unsigned int* Hr = &V2[cur][0];
    #pragma unroll
    for (int mt = 0; mt < 2; ++mt) {
      float mu[4], rs[4];
      #pragma unroll
      for (int r = 0; r < 4; ++r) {
        const int t = tt * 32 + mt * 16 + g * 4 + r;
        const float4 f0 = *(const float4*)&Lexf[t * 8];
        const float4 f1 = *(const float4*)&Lexf[t * 8 + 4];
        const float m = (f0.x + f0.z + f1.x + f1.z) * (1.0f / 128.0f);
        const float va = (f0.y + f0.w + f1.y + f1.w) * (1.0f / 128.0f) - m * m;
        mu[r] = m;
        rs[r] = rsqrtf(va + 1e-5f);
      }
      #pragma unroll
      for (int ot = 0; ot < 2; ++ot) {
        const int o = oq * 32 + ot * 16 + l15;
        const float ga = ot ? ga1 : ga0;
        const float be = ot ? be1 : be0;
        #pragma unroll
        for (int rp = 0; rp < 2; ++rp) {
          float h0 = (yac[mt][ot][rp * 2] - mu[rp * 2]) * rs[rp * 2] * ga + be;
          h0 = h0 * __builtin_amdgcn_rcpf(1.0f + __expf(-h0));
          float h1 = (yac[mt][ot][rp * 2 + 1] - mu[rp * 2 + 1]) * rs[rp * 2 + 1] * ga + be;
          h1 = h1 * __builtin_amdgcn_rcpf(1.0f + __expf(-h1));
          const int t2 = tt * 16 + mt * 8 + g * 2 + rp;
          Hr[t2 * HROW + o] = pk2(h0, h1);
        }
      }
    }
    if (i + 1 < NCHK) {
      CORRECT_STORE(&V2[cur ^ 1][0]);   // compiler inserts vmcnt wait on st here
      if (i + 2 < NCHK) LOAD_ST(kc + 2);
    }
    rawbar();   // E: Hr + next-chunk stage visible

    // ---- F: out-GEMM (Hr from LDS, Wb from regs) -> direct stores ----
    {
      f32x4 oac[2] = {};
      #pragma unroll
      for (int kt = 0; kt < 8; ++kt) {
        bf16x8 Aa0, Aa1;
        {
          union { bf16x8 v; u32x4 u; } Ax;
          Ax.u = *(const u32x4*)&Hr[(l15) * HROW + kt * 16 + g * 4];
          Aa0 = Ax.v;
          Ax.u = *(const u32x4*)&Hr[(16 + l15) * HROW + kt * 16 + g * 4];
          Aa1 = Ax.v;
        }
        oac[0] = __builtin_amdgcn_mfma_f32_16x16x32_bf16(Aa0, wf[kt], oac[0], 0, 0, 0);
        oac[1] = __builtin_amdgcn_mfma_f32_16x16x32_bf16(Aa1, wf[kt], oac[1], 0, 0, 0);
      }
      const int o = w * 16 + l15;
      #pragma unroll
      for (int mt = 0; mt < 2; ++mt) {
        float4 q;
        q.x = oac[mt][0] + bia;
        q.y = oac[mt][1] + bia;
        q.z = oac[mt][2] + bia;
        q.w = oac[mt][3] + bia;
        *(float4*)(out + ((size_t)(b * OCH + o)) * THALF + kc * 32 + mt * 16 + g * 4) = q;
      }
    }
  }
#undef LOAD_ST
#undef CORRECT_ROW
#undef CORRECT_STORE
}

// ---------------- launch ----------------
extern "C" void kernel_launch(void* const* d_in, const int* in_sizes, int n_in,
                              void* d_out, int out_size, void* d_ws, size_t ws_size,
                              hipStream_t stream) {
  const float* x    = (const float*)d_in[0];
  const float* rl   = (const float*)d_in[1];
  const float* Bc   = (const float*)d_in[2];
  const float* Cm   = (const float*)d_in[3];
  const float* lng  = (const float*)d_in[4];
  const float* lnb  = (const float*)d_in[5];
  const float* W    = (const float*)d_in[6];
  const float* bias = (const float*)d_in[7];
  float* out = (float*)d_out;

  char* ws = (char*)d_ws;
  unsigned short* BdT = (unsigned short*)(ws);            // 64 KB
  unsigned short* CT  = (unsigned short*)(ws + 65536);    // 64 KB
  unsigned short* Wb  = (unsigned short*)(ws + 131072);   // 64 KB
  float* Ad    = (float*)(ws + 196608);                   // 1 KB
  float* rL    = (float*)(ws + 197632);                   // 1 KB
  float* PWf   = (float*)(ws + 198656);                   // 32 KB
  float* carry = (float*)(ws + 231424);                   // 2 MB
  unsigned int* S = (unsigned int*)(ws + 231424 + 2097152); // 64 MB

  k_prep<<<417, 256, 0, stream>>>(rl, Bc, Cm, W, BdT, CT, Wb, Ad, rL, PWf);
  k_scan<<<BATCH * NCHUNK, 512, 0, stream>>>(x, BdT, Ad, S, carry);
  k_combine<<<64, 256, 0, stream>>>(carry, rL);
  k_apply<<<BATCH * (NCHUNK / NCHK), 512, 0, stream>>>(S, CT, Wb, PWf, Ad, carry,
                                                       lng, lnb, bias, out);
}

// Round 10
// 102.342 us; speedup vs baseline: 1.6777x; 1.0214x over previous
//
#include <hip/hip_runtime.h>

#define BATCH 8
#define CIN 128
#define OCH 128
#define T_LEN 16384
#define NS 256
#define CHUNK 64
#define NCHUNK (T_LEN / CHUNK)   // 256
#define THALF (T_LEN / 2)        // 8192
#define SCHUNK 8192              // u32 per chunk image in global: 32 rows x 256 n
#define HROW 132                 // Hr row stride (u32)
#define NCHK 4                   // chunks per apply block

typedef __attribute__((ext_vector_type(8))) short bf16x8;
typedef __attribute__((ext_vector_type(4))) float f32x4;
typedef __attribute__((ext_vector_type(4))) unsigned int u32x4;

__device__ __forceinline__ unsigned int pk2(float lo, float hi) {
  unsigned int d;
  asm("v_cvt_pk_bf16_f32 %0, %1, %2" : "=v"(d) : "v"(lo), "v"(hi));
  return d;
}
__device__ __forceinline__ unsigned short f2bf(float f) {
  unsigned int u = __float_as_uint(f);
  u += 0x7fffu + ((u >> 16) & 1u);
  return (unsigned short)(u >> 16);
}
__device__ __forceinline__ float softplusf_(float v) {
  return (v > 20.0f) ? v : log1pf(expf(v));
}
// barrier that does NOT drain vmcnt (keeps global prefetch in flight)
__device__ __forceinline__ void rawbar() {
  __builtin_amdgcn_sched_barrier(0);
  asm volatile("s_waitcnt lgkmcnt(0)" ::: "memory");
  __builtin_amdgcn_sched_barrier(0);
  __builtin_amdgcn_s_barrier();
  __builtin_amdgcn_sched_barrier(0);
}

// ---------------- prep: weights -> bf16, A_d, A_d^L, PWf[tp][n] = A_n^(2tp+1) ----------------
__global__ __launch_bounds__(256) void k_prep(
    const float* __restrict__ rl, const float* __restrict__ Bc,
    const float* __restrict__ Cm, const float* __restrict__ W,
    unsigned short* __restrict__ BdT, unsigned short* __restrict__ CT,
    unsigned short* __restrict__ Wb, float* __restrict__ Ad, float* __restrict__ rL,
    float* __restrict__ PWf)
{
  const int tid = blockIdx.x * 256 + threadIdx.x;
  if (tid < NS * CIN) {                       // BdT[n][c] = B_c[c][n] * (A_d-1)/lam
    const int n = tid >> 7, c = tid & 127;
    float lam = -softplusf_(rl[n]);
    float ad = expf(lam);
    float sc = (ad - 1.0f) / lam;
    BdT[tid] = f2bf(Bc[c * NS + n] * sc);
  } else if (tid < 2 * NS * CIN) {            // CT[o][n] = C[n][o]
    const int i = tid - NS * CIN;
    const int o = i >> 8, n = i & 255;
    CT[i] = f2bf(Cm[n * OCH + o]);
  } else if (tid < 3 * NS * CIN) {            // Wb[o][c2] = W[o][c2]
    const int i = tid - 2 * NS * CIN;
    Wb[i] = f2bf(W[i]);
  } else if (tid < 3 * NS * CIN + NS) {
    const int n = tid - 3 * NS * CIN;
    float lam = -softplusf_(rl[n]);
    Ad[n] = expf(lam);
    rL[n] = expf(lam * (float)CHUNK);
  } else if (tid < 3 * NS * CIN + NS + 32 * NS) {   // PWf[tp][n] = A_n^(2tp+1)
    const int i = tid - (3 * NS * CIN + NS);
    const int tp = i >> 8, n = i & 255;
    float lam = -softplusf_(rl[n]);
    PWf[i] = expf(lam * (float)(2 * tp + 1));
  }
}

// ---------------- chunk-carry combine: Hillis-Steele with multiplier A^L ----------------
__global__ __launch_bounds__(256) void k_combine(float* __restrict__ carry,
                                                 const float* __restrict__ rL)
{
  const int b = blockIdx.x >> 3;
  const int ng = blockIdx.x & 7;      // n-group of 32
  const int t = threadIdx.x;          // chunk index
  __shared__ float Y[32][NCHUNK];
  float* base = carry + ((size_t)b * NCHUNK + t) * NS + ng * 32;
  #pragma unroll
  for (int i4 = 0; i4 < 8; ++i4) {
    float4 q = *(const float4*)(base + i4 * 4);
    Y[i4 * 4 + 0][t] = q.x; Y[i4 * 4 + 1][t] = q.y;
    Y[i4 * 4 + 2][t] = q.z; Y[i4 * 4 + 3][t] = q.w;
  }
  float rp[32];
  #pragma unroll
  for (int i = 0; i < 32; ++i) rp[i] = rL[ng * 32 + i];
  __syncthreads();
  for (int d = 1; d < NCHUNK; d <<= 1) {
    float tmp[32];
    #pragma unroll
    for (int i = 0; i < 32; ++i) tmp[i] = (t >= d) ? Y[i][t - d] : 0.0f;
    __syncthreads();
    #pragma unroll
    for (int i = 0; i < 32; ++i) { Y[i][t] += rp[i] * tmp[i]; rp[i] *= rp[i]; }
    __syncthreads();
  }
  const int tm = (t == 0) ? 0 : (t - 1);
  #pragma unroll
  for (int i4 = 0; i4 < 8; ++i4) {
    float a = Y[i4 * 4 + 0][tm], bb = Y[i4 * 4 + 1][tm];
    float c = Y[i4 * 4 + 2][tm], dd = Y[i4 * 4 + 3][tm];
    float4 q;
    q.x = (t == 0) ? 0.0f : a;  q.y = (t == 0) ? 0.0f : bb;
    q.z = (t == 0) ? 0.0f : c;  q.w = (t == 0) ? 0.0f : dd;
    *(float4*)(base + i4 * 4) = q;
  }
}

// ---------------- k_scan: x -> v-GEMM -> scan(seed 0) -> s0 scratch + totals ----------------
__global__ __launch_bounds__(512, 4) void k_scan(
    const float* __restrict__ x,
    const unsigned short* __restrict__ BdT,
    const float* __restrict__ Ad,
    unsigned int* __restrict__ s0,
    float* __restrict__ carry)
{
  const int bid = blockIdx.x;
  const int b = bid >> 8;
  const int kc = bid & 255;
  const int tid = threadIdx.x;
  const int w = tid >> 6, l = tid & 63, l15 = l & 15, g = l >> 4;

  __shared__ __align__(16) unsigned int Xt[64 * 64];  // [t][c2 ^ ((t&7)<<2)] packed bf16 pairs

  // ---- stage x: thread -> (c2 = w*8 + (l&7), t-block = (l>>3)*8): contiguous 32B loads ----
  {
    const int c2 = w * 8 + (l & 7);
    const int t0b = (l >> 3) * 8;
    const float* r0 = x + ((size_t)(b * CIN + 2 * c2)) * T_LEN + kc * CHUNK + t0b;
    const f32x4 xa0 = *(const f32x4*)r0;
    const f32x4 xa1 = *(const f32x4*)(r0 + 4);
    const f32x4 xb0 = *(const f32x4*)(r0 + T_LEN);
    const f32x4 xb1 = *(const f32x4*)(r0 + T_LEN + 4);
    #pragma unroll
    for (int k = 0; k < 8; ++k) {
      const int t = t0b + k;
      const float va = (k < 4) ? xa0[k & 3] : xa1[k & 3];
      const float vb = (k < 4) ? xb0[k & 3] : xb1[k & 3];
      Xt[t * 64 + (c2 ^ ((t & 7) << 2))] = pk2(va, vb);
    }
  }

  // ---- per-wave B fragments (n in [32w, 32w+32)) + scan constants ----
  bf16x8 Bf[2][4];
  #pragma unroll
  for (int nt = 0; nt < 2; ++nt)
    #pragma unroll
    for (int kt = 0; kt < 4; ++kt)
      Bf[nt][kt] = *(const bf16x8*)&BdT[(w * 32 + nt * 16 + l15) * CIN + kt * 32 + g * 8];

  float A1[2], A2[2], A3[2], A4[2], A8[2], A16[2], A4G[2], M1[2], M2[2];
  #pragma unroll
  for (int nt = 0; nt < 2; ++nt) {
    const float a1 = Ad[w * 32 + nt * 16 + l15];
    A1[nt] = a1; A2[nt] = a1 * a1; A3[nt] = A2[nt] * a1; A4[nt] = A2[nt] * A2[nt];
    A8[nt] = A4[nt] * A4[nt]; A16[nt] = A8[nt] * A8[nt];
    float a4g = 1.0f;
    if (g & 1) a4g *= A4[nt];
    if (g & 2) a4g *= A8[nt];
    A4G[nt] = a4g;
    M1[nt] = (g >= 1) ? A4[nt] : 0.0f;
    M2[nt] = (g >= 2) ? A8[nt] : 0.0f;
  }
  __syncthreads();

  // ---- v-GEMM ----
  f32x4 vac[4][2] = {};
  #pragma unroll
  for (int kt = 0; kt < 4; ++kt) {
    bf16x8 afr[4];
    #pragma unroll
    for (int mt = 0; mt < 4; ++mt)
      afr[mt] = *(const bf16x8*)&Xt[(mt * 16 + l15) * 64 + ((kt * 16 + g * 4) ^ ((l15 & 7) << 2))];
    #pragma unroll
    for (int nt = 0; nt < 2; ++nt)
      #pragma unroll
      for (int mt = 0; mt < 4; ++mt)
        vac[mt][nt] = __builtin_amdgcn_mfma_f32_16x16x32_bf16(afr[mt], Bf[nt][kt], vac[mt][nt], 0, 0, 0);
  }

  // ---- in-register scan over t, seed 0 ----
  float crv[2];
  #pragma unroll
  for (int nt = 0; nt < 2; ++nt) {
    float cr = 0.0f;
    #pragma unroll
    for (int mt = 0; mt < 4; ++mt) {
      const float p0 = vac[mt][nt][0];
      const float p1 = fmaf(A1[nt], p0, vac[mt][nt][1]);
      const float p2 = fmaf(A1[nt], p1, vac[mt][nt][2]);
      const float p3 = fmaf(A1[nt], p2, vac[mt][nt][3]);
      float c0 = p3;
      float u = __shfl_up(c0, 16);
      c0 = fmaf(M1[nt], u, c0);
      u = __shfl_up(c0, 32);
      c0 = fmaf(M2[nt], u, c0);
      float e = __shfl_up(c0, 16);
      e = (g == 0) ? 0.0f : e;
      const float seed = fmaf(A4G[nt], cr, e);
      vac[mt][nt][0] = fmaf(A1[nt], seed, p0);
      vac[mt][nt][1] = fmaf(A2[nt], seed, p1);
      vac[mt][nt][2] = fmaf(A3[nt], seed, p2);
      vac[mt][nt][3] = fmaf(A4[nt], seed, p3);
      const float ctop = __shfl(c0, 48 + l15);
      cr = fmaf(A16[nt], cr, ctop);
    }
    crv[nt] = cr;
  }

  // ---- store packed s0 [tp][n] (linear, coalesced) + totals ----
  unsigned int* sc = s0 + (size_t)(b * NCHUNK + kc) * SCHUNK;
  #pragma unroll
  for (int mt = 0; mt < 4; ++mt)
    #pragma unroll
    for (int nt = 0; nt < 2; ++nt) {
      const int n = w * 32 + nt * 16 + l15;
      #pragma unroll
      for (int rp = 0; rp < 2; ++rp) {
        const int tp = mt * 8 + g * 2 + rp;
        sc[tp * 256 + n] = pk2(vac[mt][nt][rp * 2], vac[mt][nt][rp * 2 + 1]);
      }
    }
  if (g == 0) {
    #pragma unroll
    for (int nt = 0; nt < 2; ++nt)
      carry[((size_t)b * NCHUNK + kc) * NS + (w * 32 + nt * 16 + l15)] = crv[nt];
  }
}

// ---------------- k_apply: stage(+seed-correct) -> y-GEMM -> LN/SiLU -> out-GEMM ----------------
// V2 now holds the states in FINAL FRAGMENT LAYOUT: bf16 row-major [t][n], XOR-swizzled
// (16B chunk c -> c ^ ((t&7)<<2)). Correction writes it directly; y-GEMM A-frags become
// plain ds_read_b128 (no v_perm transpose). PW weights hoisted to registers (chunk-invariant).
__global__ __launch_bounds__(512, 2) void k_apply(
    const unsigned int* __restrict__ S,
    const unsigned short* __restrict__ CT,
    const unsigned short* __restrict__ Wb,
    const float* __restrict__ PWf,
    const float* __restrict__ Ad,
    const float* __restrict__ carry,
    const float* __restrict__ lng, const float* __restrict__ lnb,
    const float* __restrict__ bias,
    float* __restrict__ out)
{
  const int bid = blockIdx.x;
  const int b = bid / (NCHUNK / NCHK);
  const int kc0 = (bid % (NCHUNK / NCHK)) * NCHK;
  const int tid = threadIdx.x;
  const int w = tid >> 6, l = tid & 63, l15 = l & 15, g = l >> 4;
  const int tt = w >> 2, oq = w & 3;

  __shared__ __align__(16) unsigned short V2[2][64 * 256];  // 2 x 32 KB, swizzled bf16 [t][n]
  __shared__ __align__(16) float Lexf[64 * 8];              // 2 KB

  const f32x4 adv = *(const f32x4*)&Ad[4 * l];

  // ---- loop-invariant fragments in registers (loaded ONCE per block) ----
  bf16x8 ctf[8][2];
  #pragma unroll
  for (int kt = 0; kt < 8; ++kt)
    #pragma unroll
    for (int ot = 0; ot < 2; ++ot)
      ctf[kt][ot] = *(const bf16x8*)&CT[(oq * 32 + ot * 16 + l15) * NS + kt * 32 + g * 8];
  bf16x8 wf[8];
  #pragma unroll
  for (int kt = 0; kt < 8; ++kt)
    wf[kt] = *(const bf16x8*)&Wb[(w * 16 + l15) * NS + kt * 32 + g * 8];
  f32x4 pwv[4];
  #pragma unroll
  for (int r = 0; r < 4; ++r)
    pwv[r] = *(const f32x4*)&PWf[(r * 8 + w) * 256 + 4 * l];
  const float ga0 = lng[oq * 32 + l15],      be0 = lnb[oq * 32 + l15];
  const float ga1 = lng[oq * 32 + 16 + l15], be1 = lnb[oq * 32 + 16 + l15];
  const float bia = bias[w * 16 + l15];

  u32x4 st0, st1, st2, st3;
  f32x4 sd;

#define LOAD_ST(KC) do {                                                    \
    const unsigned int* scb_ = S + (size_t)(b * NCHUNK + (KC)) * SCHUNK;    \
    st0 = *(const u32x4*)&scb_[0 * 2048 + tid * 4];                         \
    st1 = *(const u32x4*)&scb_[1 * 2048 + tid * 4];                         \
    st2 = *(const u32x4*)&scb_[2 * 2048 + tid * 4];                         \
    st3 = *(const u32x4*)&scb_[3 * 2048 + tid * 4];                         \
    sd  = *(const f32x4*)&carry[((size_t)b * NCHUNK + (KC)) * NS + 4 * l];  \
  } while (0)

  // thread owns t-pair rows tp = RR*8+w, cols n = 4l..4l+3; writes rows 2tp (lo) and 2tp+1 (hi)
#define CORRECT_ROW(QV, RR) do {                                            \
    const float e00 = sd[0] * pwv[RR][0];                                   \
    const float e01 = sd[1] * pwv[RR][1];                                   \
    const float e02 = sd[2] * pwv[RR][2];                                   \
    const float e03 = sd[3] * pwv[RR][3];                                   \
    const float lo0 = __uint_as_float(QV[0] << 16) + e00;                   \
    const float hi0 = __uint_as_float(QV[0] & 0xffff0000u) + e00 * adv[0];  \
    const float lo1 = __uint_as_float(QV[1] << 16) + e01;                   \
    const float hi1 = __uint_as_float(QV[1] & 0xffff0000u) + e01 * adv[1];  \
    const float lo2 = __uint_as_float(QV[2] << 16) + e02;                   \
    const float hi2 = __uint_as_float(QV[2] & 0xffff0000u) + e02 * adv[2];  \
    const float lo3 = __uint_as_float(QV[3] << 16) + e03;                   \
    const float hi3 = __uint_as_float(QV[3] & 0xffff0000u) + e03 * adv[3];  \
    const int t0_ = ((RR) * 8 + w) * 2;                                     \
    const int t1_ = t0_ + 1;                                                \
    uint2 wlo; wlo.x = pk2(lo0, lo1); wlo.y = pk2(lo2, lo3);                \
    uint2 whi; whi.x = pk2(hi0, hi1); whi.y = pk2(hi2, hi3);                \
    *(uint2*)&dst_[t0_ * 256 + ((((l >> 1) ^ ((t0_ & 7) << 2)) << 3) | ((l & 1) << 2))] = wlo; \
    *(uint2*)&dst_[t1_ * 256 + ((((l >> 1) ^ ((t1_ & 7) << 2)) << 3) | ((l & 1) << 2))] = whi; \
  } while (0)

#define CORRECT_STORE(DST) do {                                             \
    unsigned short* dst_ = (DST);                                           \
    CORRECT_ROW(st0, 0);                                                    \
    CORRECT_ROW(st1, 1);                                                    \
    CORRECT_ROW(st2, 2);                                                    \
    CORRECT_ROW(st3, 3);                                                    \
  } while (0)

  // ---- prologue: load+correct chunk kc0 -> V2[0]; issue kc0+1 loads ----
  LOAD_ST(kc0);
  CORRECT_STORE(&V2[0][0]);
  LOAD_ST(kc0 + 1);
  rawbar();

  #pragma unroll 1
  for (int i = 0; i < NCHK; ++i) {
    const int cur = i & 1;
    const int kc = kc0 + i;

    // ---- B: y-GEMM (V2[cur] direct-fragment reads, CT from regs) + LN partials ----
    f32x4 yac[2][2] = {};
    #pragma unroll
    for (int kt = 0; kt < 8; ++kt) {
      bf16x8 As[2];
      #pragma unroll
      for (int mt = 0; mt < 2; ++mt) {
        const int t = tt * 32 + mt * 16 + l15;
        As[mt] = *(const bf16x8*)&V2[cur][t * 256 + (((kt * 4 + g) ^ ((t & 7) << 2)) << 3)];
      }
      #pragma unroll
      for (int ot = 0; ot < 2; ++ot)
        #pragma unroll
        for (int mt = 0; mt < 2; ++mt)
          yac[mt][ot] = __builtin_amdgcn_mfma_f32_16x16x32_bf16(As[mt], ctf[kt][ot], yac[mt][ot], 0, 0, 0);
    }
    #pragma unroll
    for (int mt = 0; mt < 2; ++mt)
      #pragma unroll
      for (int r = 0; r < 4; ++r) {
        float s1 = yac[mt][0][r] + yac[mt][1][r];
        float s2 = yac[mt][0][r] * yac[mt][0][r] + yac[mt][1][r] * yac[mt][1][r];
        #pragma unroll
        for (int d = 1; d < 16; d <<= 1) { s1 += __shfl_xor(s1, d); s2 += __shfl_xor(s2, d); }
        if (l15 == 0) {
          const int t = tt * 32 + mt * 16 + g * 4 + r;
          *(float2*)&Lexf[t * 8 + oq * 2] = make_float2(s1, s2);
        }
      }
    rawbar();   // C: Lex visible; V2[cur] fully read

    // ---- D: LN finish + SiLU -> Hr (aliases V2[cur]); staged correction -> V2[cur^1] ----
    unsigned int* Hr = (unsigned int*)&V2[cur][0];
    #pragma unroll
    for (int mt = 0; mt < 2; ++mt) {
      float mu[4], rs[4];
      #pragma unroll
      for (int r = 0; r < 4; ++r) {
        const int t = tt * 32 + mt * 16 + g * 4 + r;
        const float4 f0 = *(const float4*)&Lexf[t * 8];
        const float4 f1 = *(const float4*)&Lexf[t * 8 + 4];
        const float m = (f0.x + f0.z + f1.x + f1.z) * (1.0f / 128.0f);
        const float va = (f0.y + f0.w + f1.y + f1.w) * (1.0f / 128.0f) - m * m;
        mu[r] = m;
        rs[r] = rsqrtf(va + 1e-5f);
      }
      #pragma unroll
      for (int ot = 0; ot < 2; ++ot) {
        const int o = oq * 32 + ot * 16 + l15;
        const float ga = ot ? ga1 : ga0;
        const float be = ot ? be1 : be0;
        #pragma unroll
        for (int rp = 0; rp < 2; ++rp) {
          float h0 = (yac[mt][ot][rp * 2] - mu[rp * 2]) * rs[rp * 2] * ga + be;
          h0 = h0 * __builtin_amdgcn_rcpf(1.0f + __expf(-h0));
          float h1 = (yac[mt][ot][rp * 2 + 1] - mu[rp * 2 + 1]) * rs[rp * 2 + 1] * ga + be;
          h1 = h1 * __builtin_amdgcn_rcpf(1.0f + __expf(-h1));
          const int t2 = tt * 16 + mt * 8 + g * 2 + rp;
          Hr[t2 * HROW + o] = pk2(h0, h1);
        }
      }
    }
    if (i + 1 < NCHK) {
      CORRECT_STORE(&V2[cur ^ 1][0]);   // compiler inserts vmcnt wait on st here
      if (i + 2 < NCHK) LOAD_ST(kc + 2);
    }
    rawbar();   // E: Hr + next-chunk stage visible

    // ---- F: out-GEMM (Hr from LDS, Wb from regs) -> direct stores ----
    {
      f32x4 oac[2] = {};
      #pragma unroll
      for (int kt = 0; kt < 8; ++kt) {
        bf16x8 Aa0, Aa1;
        {
          union { bf16x8 v; u32x4 u; } Ax;
          Ax.u = *(const u32x4*)&Hr[(l15) * HROW + kt * 16 + g * 4];
          Aa0 = Ax.v;
          Ax.u = *(const u32x4*)&Hr[(16 + l15) * HROW + kt * 16 + g * 4];
          Aa1 = Ax.v;
        }
        oac[0] = __builtin_amdgcn_mfma_f32_16x16x32_bf16(Aa0, wf[kt], oac[0], 0, 0, 0);
        oac[1] = __builtin_amdgcn_mfma_f32_16x16x32_bf16(Aa1, wf[kt], oac[1], 0, 0, 0);
      }
      const int o = w * 16 + l15;
      #pragma unroll
      for (int mt = 0; mt < 2; ++mt) {
        float4 q;
        q.x = oac[mt][0] + bia;
        q.y = oac[mt][1] + bia;
        q.z = oac[mt][2] + bia;
        q.w = oac[mt][3] + bia;
        *(float4*)(out + ((size_t)(b * OCH + o)) * THALF + kc * 32 + mt * 16 + g * 4) = q;
      }
    }
  }
#undef LOAD_ST
#undef CORRECT_ROW
#undef CORRECT_STORE
}

// ---------------- launch ----------------
extern "C" void kernel_launch(void* const* d_in, const int* in_sizes, int n_in,
                              void* d_out, int out_size, void* d_ws, size_t ws_size,
                              hipStream_t stream) {
  const float* x    = (const float*)d_in[0];
  const float* rl   = (const float*)d_in[1];
  const float* Bc   = (const float*)d_in[2];
  const float* Cm   = (const float*)d_in[3];
  const float* lng  = (const float*)d_in[4];
  const float* lnb  = (const float*)d_in[5];
  const float* W    = (const float*)d_in[6];
  const float* bias = (const float*)d_in[7];
  float* out = (float*)d_out;

  char* ws = (char*)d_ws;
  unsigned short* BdT = (unsigned short*)(ws);            // 64 KB
  unsigned short* CT  = (unsigned short*)(ws + 65536);    // 64 KB
  unsigned short* Wb  = (unsigned short*)(ws + 131072);   // 64 KB
  float* Ad    = (float*)(ws + 196608);                   // 1 KB
  float* rL    = (float*)(ws + 197632);                   // 1 KB
  float* PWf   = (float*)(ws + 198656);                   // 32 KB
  float* carry = (float*)(ws + 231424);                   // 2 MB
  unsigned int* S = (unsigned int*)(ws + 231424 + 2097152); // 64 MB

  k_prep<<<417, 256, 0, stream>>>(rl, Bc, Cm, W, BdT, CT, Wb, Ad, rL, PWf);
  k_scan<<<BATCH * NCHUNK, 512, 0, stream>>>(x, BdT, Ad, S, carry);
  k_combine<<<64, 256, 0, stream>>>(carry, rL);
  k_apply<<<BATCH * (NCHUNK / NCHK), 512, 0, stream>>>(S, CT, Wb, PWf, Ad, carry,
                                                       lng, lnb, bias, out);
}

// Round 11
// 101.758 us; speedup vs baseline: 1.6874x; 1.0057x over previous
//
#include <hip/hip_runtime.h>

#define BATCH 8
#define CIN 128
#define OCH 128
#define T_LEN 16384
#define NS 256
#define CHUNK 64
#define NCHUNK (T_LEN / CHUNK)   // 256
#define THALF (T_LEN / 2)        // 8192
#define SCHUNK 8192              // u32 per chunk image in global: 32 rows x 256 n
#define HROW 132                 // Hr row stride (u32)
#define NCHK 4                   // chunks per apply block

typedef __attribute__((ext_vector_type(8))) short bf16x8;
typedef __attribute__((ext_vector_type(4))) float f32x4;
typedef __attribute__((ext_vector_type(4))) unsigned int u32x4;

__device__ __forceinline__ unsigned int pk2(float lo, float hi) {
  unsigned int d;
  asm("v_cvt_pk_bf16_f32 %0, %1, %2" : "=v"(d) : "v"(lo), "v"(hi));
  return d;
}
__device__ __forceinline__ unsigned short f2bf(float f) {
  unsigned int u = __float_as_uint(f);
  u += 0x7fffu + ((u >> 16) & 1u);
  return (unsigned short)(u >> 16);
}
__device__ __forceinline__ float softplusf_(float v) {
  return (v > 20.0f) ? v : log1pf(expf(v));
}
// barrier that does NOT drain vmcnt (keeps global prefetch in flight)
__device__ __forceinline__ void rawbar() {
  __builtin_amdgcn_sched_barrier(0);
  asm volatile("s_waitcnt lgkmcnt(0)" ::: "memory");
  __builtin_amdgcn_sched_barrier(0);
  __builtin_amdgcn_s_barrier();
  __builtin_amdgcn_sched_barrier(0);
}

// ---------------- prep: weights -> bf16, A_d, A_d^L, PWf[tp][n] = A_n^(2tp+1) ----------------
__global__ __launch_bounds__(256) void k_prep(
    const float* __restrict__ rl, const float* __restrict__ Bc,
    const float* __restrict__ Cm, const float* __restrict__ W,
    unsigned short* __restrict__ BdT, unsigned short* __restrict__ CT,
    unsigned short* __restrict__ Wb, float* __restrict__ Ad, float* __restrict__ rL,
    float* __restrict__ PWf)
{
  const int tid = blockIdx.x * 256 + threadIdx.x;
  if (tid < NS * CIN) {                       // BdT[n][c] = B_c[c][n] * (A_d-1)/lam
    const int n = tid >> 7, c = tid & 127;
    float lam = -softplusf_(rl[n]);
    float ad = expf(lam);
    float sc = (ad - 1.0f) / lam;
    BdT[tid] = f2bf(Bc[c * NS + n] * sc);
  } else if (tid < 2 * NS * CIN) {            // CT[o][n] = C[n][o]
    const int i = tid - NS * CIN;
    const int o = i >> 8, n = i & 255;
    CT[i] = f2bf(Cm[n * OCH + o]);
  } else if (tid < 3 * NS * CIN) {            // Wb[o][c2] = W[o][c2]
    const int i = tid - 2 * NS * CIN;
    Wb[i] = f2bf(W[i]);
  } else if (tid < 3 * NS * CIN + NS) {
    const int n = tid - 3 * NS * CIN;
    float lam = -softplusf_(rl[n]);
    Ad[n] = expf(lam);
    rL[n] = expf(lam * (float)CHUNK);
  } else if (tid < 3 * NS * CIN + NS + 32 * NS) {   // PWf[tp][n] = A_n^(2tp+1)
    const int i = tid - (3 * NS * CIN + NS);
    const int tp = i >> 8, n = i & 255;
    float lam = -softplusf_(rl[n]);
    PWf[i] = expf(lam * (float)(2 * tp + 1));
  }
}

// ---------------- chunk-carry combine: Hillis-Steele with multiplier A^L ----------------
__global__ __launch_bounds__(256) void k_combine(float* __restrict__ carry,
                                                 const float* __restrict__ rL)
{
  const int b = blockIdx.x >> 3;
  const int ng = blockIdx.x & 7;      // n-group of 32
  const int t = threadIdx.x;          // chunk index
  __shared__ float Y[32][NCHUNK];
  float* base = carry + ((size_t)b * NCHUNK + t) * NS + ng * 32;
  #pragma unroll
  for (int i4 = 0; i4 < 8; ++i4) {
    float4 q = *(const float4*)(base + i4 * 4);
    Y[i4 * 4 + 0][t] = q.x; Y[i4 * 4 + 1][t] = q.y;
    Y[i4 * 4 + 2][t] = q.z; Y[i4 * 4 + 3][t] = q.w;
  }
  float rp[32];
  #pragma unroll
  for (int i = 0; i < 32; ++i) rp[i] = rL[ng * 32 + i];
  __syncthreads();
  for (int d = 1; d < NCHUNK; d <<= 1) {
    float tmp[32];
    #pragma unroll
    for (int i = 0; i < 32; ++i) tmp[i] = (t >= d) ? Y[i][t - d] : 0.0f;
    __syncthreads();
    #pragma unroll
    for (int i = 0; i < 32; ++i) { Y[i][t] += rp[i] * tmp[i]; rp[i] *= rp[i]; }
    __syncthreads();
  }
  const int tm = (t == 0) ? 0 : (t - 1);
  #pragma unroll
  for (int i4 = 0; i4 < 8; ++i4) {
    float a = Y[i4 * 4 + 0][tm], bb = Y[i4 * 4 + 1][tm];
    float c = Y[i4 * 4 + 2][tm], dd = Y[i4 * 4 + 3][tm];
    float4 q;
    q.x = (t == 0) ? 0.0f : a;  q.y = (t == 0) ? 0.0f : bb;
    q.z = (t == 0) ? 0.0f : c;  q.w = (t == 0) ? 0.0f : dd;
    *(float4*)(base + i4 * 4) = q;
  }
}

// ---------------- k_scan: x -> v-GEMM -> scan(seed 0) -> s0 scratch + totals ----------------
__global__ __launch_bounds__(512, 4) void k_scan(
    const float* __restrict__ x,
    const unsigned short* __restrict__ BdT,
    const float* __restrict__ Ad,
    unsigned int* __restrict__ s0,
    float* __restrict__ carry)
{
  const int bid = blockIdx.x;
  const int b = bid >> 8;
  const int kc = bid & 255;
  const int tid = threadIdx.x;
  const int w = tid >> 6, l = tid & 63, l15 = l & 15, g = l >> 4;

  __shared__ __align__(16) unsigned int Xt[64 * 64];  // [t][c2 ^ ((t&7)<<2)] packed bf16 pairs

  // ---- stage x: thread -> (c2 = w*8 + (l&7), t-block = (l>>3)*8): contiguous 32B loads ----
  {
    const int c2 = w * 8 + (l & 7);
    const int t0b = (l >> 3) * 8;
    const float* r0 = x + ((size_t)(b * CIN + 2 * c2)) * T_LEN + kc * CHUNK + t0b;
    const f32x4 xa0 = *(const f32x4*)r0;
    const f32x4 xa1 = *(const f32x4*)(r0 + 4);
    const f32x4 xb0 = *(const f32x4*)(r0 + T_LEN);
    const f32x4 xb1 = *(const f32x4*)(r0 + T_LEN + 4);
    #pragma unroll
    for (int k = 0; k < 8; ++k) {
      const int t = t0b + k;
      const float va = (k < 4) ? xa0[k & 3] : xa1[k & 3];
      const float vb = (k < 4) ? xb0[k & 3] : xb1[k & 3];
      Xt[t * 64 + (c2 ^ ((t & 7) << 2))] = pk2(va, vb);
    }
  }

  // ---- per-wave B fragments (n in [32w, 32w+32)) + scan constants ----
  bf16x8 Bf[2][4];
  #pragma unroll
  for (int nt = 0; nt < 2; ++nt)
    #pragma unroll
    for (int kt = 0; kt < 4; ++kt)
      Bf[nt][kt] = *(const bf16x8*)&BdT[(w * 32 + nt * 16 + l15) * CIN + kt * 32 + g * 8];

  float A1[2], A2[2], A3[2], A4[2], A8[2], A16[2], A4G[2], M1[2], M2[2];
  #pragma unroll
  for (int nt = 0; nt < 2; ++nt) {
    const float a1 = Ad[w * 32 + nt * 16 + l15];
    A1[nt] = a1; A2[nt] = a1 * a1; A3[nt] = A2[nt] * a1; A4[nt] = A2[nt] * A2[nt];
    A8[nt] = A4[nt] * A4[nt]; A16[nt] = A8[nt] * A8[nt];
    float a4g = 1.0f;
    if (g & 1) a4g *= A4[nt];
    if (g & 2) a4g *= A8[nt];
    A4G[nt] = a4g;
    M1[nt] = (g >= 1) ? A4[nt] : 0.0f;
    M2[nt] = (g >= 2) ? A8[nt] : 0.0f;
  }
  __syncthreads();

  // ---- v-GEMM ----
  f32x4 vac[4][2] = {};
  #pragma unroll
  for (int kt = 0; kt < 4; ++kt) {
    bf16x8 afr[4];
    #pragma unroll
    for (int mt = 0; mt < 4; ++mt)
      afr[mt] = *(const bf16x8*)&Xt[(mt * 16 + l15) * 64 + ((kt * 16 + g * 4) ^ ((l15 & 7) << 2))];
    #pragma unroll
    for (int nt = 0; nt < 2; ++nt)
      #pragma unroll
      for (int mt = 0; mt < 4; ++mt)
        vac[mt][nt] = __builtin_amdgcn_mfma_f32_16x16x32_bf16(afr[mt], Bf[nt][kt], vac[mt][nt], 0, 0, 0);
  }

  // ---- in-register scan over t, seed 0 ----
  float crv[2];
  #pragma unroll
  for (int nt = 0; nt < 2; ++nt) {
    float cr = 0.0f;
    #pragma unroll
    for (int mt = 0; mt < 4; ++mt) {
      const float p0 = vac[mt][nt][0];
      const float p1 = fmaf(A1[nt], p0, vac[mt][nt][1]);
      const float p2 = fmaf(A1[nt], p1, vac[mt][nt][2]);
      const float p3 = fmaf(A1[nt], p2, vac[mt][nt][3]);
      float c0 = p3;
      float u = __shfl_up(c0, 16);
      c0 = fmaf(M1[nt], u, c0);
      u = __shfl_up(c0, 32);
      c0 = fmaf(M2[nt], u, c0);
      float e = __shfl_up(c0, 16);
      e = (g == 0) ? 0.0f : e;
      const float seed = fmaf(A4G[nt], cr, e);
      vac[mt][nt][0] = fmaf(A1[nt], seed, p0);
      vac[mt][nt][1] = fmaf(A2[nt], seed, p1);
      vac[mt][nt][2] = fmaf(A3[nt], seed, p2);
      vac[mt][nt][3] = fmaf(A4[nt], seed, p3);
      const float ctop = __shfl(c0, 48 + l15);
      cr = fmaf(A16[nt], cr, ctop);
    }
    crv[nt] = cr;
  }

  // ---- store packed s0 [tp][n] (linear, coalesced) + totals ----
  unsigned int* sc = s0 + (size_t)(b * NCHUNK + kc) * SCHUNK;
  #pragma unroll
  for (int mt = 0; mt < 4; ++mt)
    #pragma unroll
    for (int nt = 0; nt < 2; ++nt) {
      const int n = w * 32 + nt * 16 + l15;
      #pragma unroll
      for (int rp = 0; rp < 2; ++rp) {
        const int tp = mt * 8 + g * 2 + rp;
        sc[tp * 256 + n] = pk2(vac[mt][nt][rp * 2], vac[mt][nt][rp * 2 + 1]);
      }
    }
  if (g == 0) {
    #pragma unroll
    for (int nt = 0; nt < 2; ++nt)
      carry[((size_t)b * NCHUNK + kc) * NS + (w * 32 + nt * 16 + l15)] = crv[nt];
  }
}

// ---------------- k_apply: stage(+seed-correct) -> y-GEMM -> LN/SiLU -> out-GEMM ----------------
// R11: SINGLE V2 buffer + separate Hr -> LDS 51.7 KB (was 67.6). The 66 KB footprint was
// limiting residency to ~1 block/CU (Occupancy ~20% vs R5's 61% at 19 KB); the double
// buffer is redundant because the barrier before phase D already guarantees V2 is fully
// read before CORRECT_STORE overwrites it. st registers keep the global prefetch depth.
__global__ __launch_bounds__(512, 2) void k_apply(
    const unsigned int* __restrict__ S,
    const unsigned short* __restrict__ CT,
    const unsigned short* __restrict__ Wb,
    const float* __restrict__ PWf,
    const float* __restrict__ Ad,
    const float* __restrict__ carry,
    const float* __restrict__ lng, const float* __restrict__ lnb,
    const float* __restrict__ bias,
    float* __restrict__ out)
{
  const int bid = blockIdx.x;
  const int b = bid / (NCHUNK / NCHK);
  const int kc0 = (bid % (NCHUNK / NCHK)) * NCHK;
  const int tid = threadIdx.x;
  const int w = tid >> 6, l = tid & 63, l15 = l & 15, g = l >> 4;
  const int tt = w >> 2, oq = w & 3;

  __shared__ __align__(16) unsigned short V2[64 * 256];  // 32 KB, swizzled bf16 [t][n]
  __shared__ __align__(16) unsigned int Hr[32 * HROW];   // 16.9 KB
  __shared__ __align__(16) float Lexf[64 * 8];           // 2 KB

  const f32x4 adv = *(const f32x4*)&Ad[4 * l];

  // ---- loop-invariant fragments in registers (loaded ONCE per block) ----
  bf16x8 ctf[8][2];
  #pragma unroll
  for (int kt = 0; kt < 8; ++kt)
    #pragma unroll
    for (int ot = 0; ot < 2; ++ot)
      ctf[kt][ot] = *(const bf16x8*)&CT[(oq * 32 + ot * 16 + l15) * NS + kt * 32 + g * 8];
  bf16x8 wf[8];
  #pragma unroll
  for (int kt = 0; kt < 8; ++kt)
    wf[kt] = *(const bf16x8*)&Wb[(w * 16 + l15) * NS + kt * 32 + g * 8];
  f32x4 pwv[4];
  #pragma unroll
  for (int r = 0; r < 4; ++r)
    pwv[r] = *(const f32x4*)&PWf[(r * 8 + w) * 256 + 4 * l];
  const float ga0 = lng[oq * 32 + l15],      be0 = lnb[oq * 32 + l15];
  const float ga1 = lng[oq * 32 + 16 + l15], be1 = lnb[oq * 32 + 16 + l15];
  const float bia = bias[w * 16 + l15];

  u32x4 st0, st1, st2, st3;
  f32x4 sd;

#define LOAD_ST(KC) do {                                                    \
    const unsigned int* scb_ = S + (size_t)(b * NCHUNK + (KC)) * SCHUNK;    \
    st0 = *(const u32x4*)&scb_[0 * 2048 + tid * 4];                         \
    st1 = *(const u32x4*)&scb_[1 * 2048 + tid * 4];                         \
    st2 = *(const u32x4*)&scb_[2 * 2048 + tid * 4];                         \
    st3 = *(const u32x4*)&scb_[3 * 2048 + tid * 4];                         \
    sd  = *(const f32x4*)&carry[((size_t)b * NCHUNK + (KC)) * NS + 4 * l];  \
  } while (0)

  // thread owns t-pair rows tp = RR*8+w, cols n = 4l..4l+3; writes rows 2tp (lo) and 2tp+1 (hi)
#define CORRECT_ROW(QV, RR) do {                                            \
    const float e00 = sd[0] * pwv[RR][0];                                   \
    const float e01 = sd[1] * pwv[RR][1];                                   \
    const float e02 = sd[2] * pwv[RR][2];                                   \
    const float e03 = sd[3] * pwv[RR][3];                                   \
    const float lo0 = __uint_as_float(QV[0] << 16) + e00;                   \
    const float hi0 = __uint_as_float(QV[0] & 0xffff0000u) + e00 * adv[0];  \
    const float lo1 = __uint_as_float(QV[1] << 16) + e01;                   \
    const float hi1 = __uint_as_float(QV[1] & 0xffff0000u) + e01 * adv[1];  \
    const float lo2 = __uint_as_float(QV[2] << 16) + e02;                   \
    const float hi2 = __uint_as_float(QV[2] & 0xffff0000u) + e02 * adv[2];  \
    const float lo3 = __uint_as_float(QV[3] << 16) + e03;                   \
    const float hi3 = __uint_as_float(QV[3] & 0xffff0000u) + e03 * adv[3];  \
    const int t0_ = ((RR) * 8 + w) * 2;                                     \
    const int t1_ = t0_ + 1;                                                \
    uint2 wlo; wlo.x = pk2(lo0, lo1); wlo.y = pk2(lo2, lo3);                \
    uint2 whi; whi.x = pk2(hi0, hi1); whi.y = pk2(hi2, hi3);                \
    *(uint2*)&V2[t0_ * 256 + ((((l >> 1) ^ ((t0_ & 7) << 2)) << 3) | ((l & 1) << 2))] = wlo; \
    *(uint2*)&V2[t1_ * 256 + ((((l >> 1) ^ ((t1_ & 7) << 2)) << 3) | ((l & 1) << 2))] = whi; \
  } while (0)

#define CORRECT_STORE() do {                                                \
    CORRECT_ROW(st0, 0);                                                    \
    CORRECT_ROW(st1, 1);                                                    \
    CORRECT_ROW(st2, 2);                                                    \
    CORRECT_ROW(st3, 3);                                                    \
  } while (0)

  // ---- prologue: load+correct chunk kc0 -> V2; issue kc0+1 loads ----
  LOAD_ST(kc0);
  CORRECT_STORE();
  LOAD_ST(kc0 + 1);
  rawbar();

  #pragma unroll 1
  for (int i = 0; i < NCHK; ++i) {
    const int kc = kc0 + i;

    // ---- B: y-GEMM (V2 direct-fragment reads, CT from regs) + LN partials ----
    f32x4 yac[2][2] = {};
    #pragma unroll
    for (int kt = 0; kt < 8; ++kt) {
      bf16x8 As[2];
      #pragma unroll
      for (int mt = 0; mt < 2; ++mt) {
        const int t = tt * 32 + mt * 16 + l15;
        As[mt] = *(const bf16x8*)&V2[t * 256 + (((kt * 4 + g) ^ ((t & 7) << 2)) << 3)];
      }
      #pragma unroll
      for (int ot = 0; ot < 2; ++ot)
        #pragma unroll
        for (int mt = 0; mt < 2; ++mt)
          yac[mt][ot] = __builtin_amdgcn_mfma_f32_16x16x32_bf16(As[mt], ctf[kt][ot], yac[mt][ot], 0, 0, 0);
    }
    #pragma unroll
    for (int mt = 0; mt < 2; ++mt)
      #pragma unroll
      for (int r = 0; r < 4; ++r) {
        float s1 = yac[mt][0][r] + yac[mt][1][r];
        float s2 = yac[mt][0][r] * yac[mt][0][r] + yac[mt][1][r] * yac[mt][1][r];
        #pragma unroll
        for (int d = 1; d < 16; d <<= 1) { s1 += __shfl_xor(s1, d); s2 += __shfl_xor(s2, d); }
        if (l15 == 0) {
          const int t = tt * 32 + mt * 16 + g * 4 + r;
          *(float2*)&Lexf[t * 8 + oq * 2] = make_float2(s1, s2);
        }
      }
    rawbar();   // C: Lex visible; V2 fully read

    // ---- D: LN finish + SiLU -> Hr; staged correction for next chunk -> V2 ----
    #pragma unroll
    for (int mt = 0; mt < 2; ++mt) {
      float mu[4], rs[4];
      #pragma unroll
      for (int r = 0; r < 4; ++r) {
        const int t = tt * 32 + mt * 16 + g * 4 + r;
        const float4 f0 = *(const float4*)&Lexf[t * 8];
        const float4 f1 = *(const float4*)&Lexf[t * 8 + 4];
        const float m = (f0.x + f0.z + f1.x + f1.z) * (1.0f / 128.0f);
        const float va = (f0.y + f0.w + f1.y + f1.w) * (1.0f / 128.0f) - m * m;
        mu[r] = m;
        rs[r] = rsqrtf(va + 1e-5f);
      }
      #pragma unroll
      for (int ot = 0; ot < 2; ++ot) {
        const int o = oq * 32 + ot * 16 + l15;
        const float ga = ot ? ga1 : ga0;
        const float be = ot ? be1 : be0;
        #pragma unroll
        for (int rp = 0; rp < 2; ++rp) {
          float h0 = (yac[mt][ot][rp * 2] - mu[rp * 2]) * rs[rp * 2] * ga + be;
          h0 = h0 * __builtin_amdgcn_rcpf(1.0f + __expf(-h0));
          float h1 = (yac[mt][ot][rp * 2 + 1] - mu[rp * 2 + 1]) * rs[rp * 2 + 1] * ga + be;
          h1 = h1 * __builtin_amdgcn_rcpf(1.0f + __expf(-h1));
          const int t2 = tt * 16 + mt * 8 + g * 2 + rp;
          Hr[t2 * HROW + o] = pk2(h0, h1);
        }
      }
    }
    if (i + 1 < NCHK) {
      CORRECT_STORE();   // overwrites V2 with chunk i+1 (fully read at barC)
      if (i + 2 < NCHK) LOAD_ST(kc + 2);
    }
    rawbar();   // E: Hr + next-chunk V2 visible

    // ---- F: out-GEMM (Hr from LDS, Wb from regs) -> direct stores ----
    {
      f32x4 oac[2] = {};
      #pragma unroll
      for (int kt = 0; kt < 8; ++kt) {
        bf16x8 Aa0, Aa1;
        {
          union { bf16x8 v; u32x4 u; } Ax;
          Ax.u = *(const u32x4*)&Hr[(l15) * HROW + kt * 16 + g * 4];
          Aa0 = Ax.v;
          Ax.u = *(const u32x4*)&Hr[(16 + l15) * HROW + kt * 16 + g * 4];
          Aa1 = Ax.v;
        }
        oac[0] = __builtin_amdgcn_mfma_f32_16x16x32_bf16(Aa0, wf[kt], oac[0], 0, 0, 0);
        oac[1] = __builtin_amdgcn_mfma_f32_16x16x32_bf16(Aa1, wf[kt], oac[1], 0, 0, 0);
      }
      const int o = w * 16 + l15;
      #pragma unroll
      for (int mt = 0; mt < 2; ++mt) {
        float4 q;
        q.x = oac[mt][0] + bia;
        q.y = oac[mt][1] + bia;
        q.z = oac[mt][2] + bia;
        q.w = oac[mt][3] + bia;
        *(float4*)(out + ((size_t)(b * OCH + o)) * THALF + kc * 32 + mt * 16 + g * 4) = q;
      }
    }
  }
#undef LOAD_ST
#undef CORRECT_ROW
#undef CORRECT_STORE
}

// ---------------- launch ----------------
extern "C" void kernel_launch(void* const* d_in, const int* in_sizes, int n_in,
                              void* d_out, int out_size, void* d_ws, size_t ws_size,
                              hipStream_t stream) {
  const float* x    = (const float*)d_in[0];
  const float* rl   = (const float*)d_in[1];
  const float* Bc   = (const float*)d_in[2];
  const float* Cm   = (const float*)d_in[3];
  const float* lng  = (const float*)d_in[4];
  const float* lnb  = (const float*)d_in[5];
  const float* W    = (const float*)d_in[6];
  const float* bias = (const float*)d_in[7];
  float* out = (float*)d_out;

  char* ws = (char*)d_ws;
  unsigned short* BdT = (unsigned short*)(ws);            // 64 KB
  unsigned short* CT  = (unsigned short*)(ws + 65536);    // 64 KB
  unsigned short* Wb  = (unsigned short*)(ws + 131072);   // 64 KB
  float* Ad    = (float*)(ws + 196608);                   // 1 KB
  float* rL    = (float*)(ws + 197632);                   // 1 KB
  float* PWf   = (float*)(ws + 198656);                   // 32 KB
  float* carry = (float*)(ws + 231424);                   // 2 MB
  unsigned int* S = (unsigned int*)(ws + 231424 + 2097152); // 64 MB

  k_prep<<<417, 256, 0, stream>>>(rl, Bc, Cm, W, BdT, CT, Wb, Ad, rL, PWf);
  k_scan<<<BATCH * NCHUNK, 512, 0, stream>>>(x, BdT, Ad, S, carry);
  k_combine<<<64, 256, 0, stream>>>(carry, rL);
  k_apply<<<BATCH * (NCHUNK / NCHK), 512, 0, stream>>>(S, CT, Wb, PWf, Ad, carry,
                                                       lng, lnb, bias, out);
}